// Round 9
// baseline (488.258 us; speedup 1.0000x reference)
//
#include <hip/hip_runtime.h>

typedef __bf16 bf16;
typedef bf16 bf16x8 __attribute__((ext_vector_type(8)));
typedef bf16 bf16x4 __attribute__((ext_vector_type(4)));
typedef float f32x4 __attribute__((ext_vector_type(4)));

// ---------------------------------------------------------------------------
// async global->LDS 16B copy (wave-uniform LDS base + lane*16 placement)
// ---------------------------------------------------------------------------
static __device__ __forceinline__ void async16(const void* g, void* l) {
  __builtin_amdgcn_global_load_lds((__attribute__((address_space(1))) void*)g,
                                   (__attribute__((address_space(3))) void*)l,
                                   16, 0, 0);
}

// DPP row_ror:N within 16-lane rows (VALU-only cross-lane; no LDS pipe).
template <int N>
static __device__ __forceinline__ float ror16(float x) {
  const int y =
      __builtin_amdgcn_update_dpp(0, __float_as_int(x), 0x120 | N, 0xf, 0xf, true);
  return __int_as_float(y);
}
static __device__ __forceinline__ float rowmax16(float x) {
  x = fmaxf(x, ror16<8>(x));
  x = fmaxf(x, ror16<4>(x));
  x = fmaxf(x, ror16<2>(x));
  x = fmaxf(x, ror16<1>(x));
  return x;
}
static __device__ __forceinline__ float rowsum16(float x) {
  x += ror16<8>(x);
  x += ror16<4>(x);
  x += ror16<2>(x);
  x += ror16<1>(x);
  return x;
}

// ---------------------------------------------------------------------------
// Weight f32 -> bf16 conversion (ternary {-1,0,1}: exact in bf16).
// ---------------------------------------------------------------------------
__global__ __launch_bounds__(256) void cvt4(const float* __restrict__ a,
                                            const float* __restrict__ b,
                                            const float* __restrict__ c,
                                            const float* __restrict__ d,
                                            bf16* __restrict__ dst) {
  const size_t i = ((size_t)blockIdx.x * 256 + threadIdx.x) * 4;
  const size_t M1 = 1u << 20;
  const float* src = (i < M1) ? a : (i < 2 * M1) ? b : (i < 3 * M1) ? c : d;
  const size_t off = i & (M1 - 1);
  const float4 v = *(const float4*)(src + off);
  bf16x4 o = {(bf16)v.x, (bf16)v.y, (bf16)v.z, (bf16)v.w};
  *(bf16x4*)(dst + i) = o;
}

__global__ __launch_bounds__(256) void cvt2(const float* __restrict__ a,
                                            const float* __restrict__ b,
                                            bf16* __restrict__ dst) {
  const size_t i = ((size_t)blockIdx.x * 256 + threadIdx.x) * 4;
  const size_t M4 = 4u << 20;
  const float* src = (i < M4) ? a : b;
  const size_t off = (i < M4) ? i : i - M4;
  const float4 v = *(const float4*)(src + off);
  bf16x4 o = {(bf16)v.x, (bf16)v.y, (bf16)v.z, (bf16)v.w};
  *(bf16x4*)(dst + i) = o;
}

// ---------------------------------------------------------------------------
// GEMM: C[M,N] = A[M,K] * B[N,K]^T  (+ optional second A accumulated, epilogue)
// EPI: 0 = f32 store, 2 = f32(acc + R[f32]), 3 = bf16 gelu(acc),
//      5 = bf16 store transposed to V^T global layout (b,h,d,t)
// smem: caller-provided (>= 8192 bf16) — avoids duplicate static LDS when a
// kernel has multiple gemm bodies (round-8 bug: 64 KB LDS block for qkv).
// ---------------------------------------------------------------------------
template <int EPI, bool SPLIT>
static __device__ __forceinline__ void gemm_body(
    const bf16* __restrict__ A, const bf16* __restrict__ A2,
    const bf16* __restrict__ B, void* __restrict__ Cv,
    const float* __restrict__ R, bf16* smem, int col0, int row0, int M, int N,
    int K) {
  bf16* sA = smem;         // 128 x 32
  bf16* sB = smem + 4096;  // 128 x 32
  const int tid = threadIdx.x;
  const int lane = tid & 63;
  const int wid = tid >> 6;
  const int wm = wid >> 1, wn = wid & 1;

  f32x4 acc[4][4];
  const f32x4 fzero = {0.f, 0.f, 0.f, 0.f};
#pragma unroll
  for (int i = 0; i < 4; ++i)
#pragma unroll
    for (int j = 0; j < 4; ++j) acc[i][j] = fzero;

  const int nk = K >> 5;
  const int total = SPLIT ? (nk << 1) : nk;
  const int r0 = tid >> 2, c0 = (tid & 3) << 3;
  const int r1 = (256 + tid) >> 2, c1 = ((256 + tid) & 3) << 3;
  bf16* lA0 = sA + (wid << 6) * 8;  // wave-uniform LDS bases
  bf16* lA1 = sA + (256 + (wid << 6)) * 8;
  bf16* lB0 = sB + (wid << 6) * 8;
  bf16* lB1 = sB + (256 + (wid << 6)) * 8;

  for (int kt = 0; kt < total; ++kt) {
    const int kk = (kt < nk) ? kt : kt - nk;
    const bf16* Ap = (SPLIT && kt >= nk) ? A2 : A;
    const int k0 = kk << 5;
    async16(Ap + (size_t)(row0 + r0) * K + k0 + c0, lA0);
    async16(Ap + (size_t)(row0 + r1) * K + k0 + c1, lA1);
    async16(B + (size_t)(col0 + r0) * K + k0 + c0, lB0);
    async16(B + (size_t)(col0 + r1) * K + k0 + c1, lB1);
    __syncthreads();
    const int fr = lane & 15, fq = (lane >> 4) << 3;
    bf16x8 af[4], bfr[4];
#pragma unroll
    for (int i = 0; i < 4; ++i)
      af[i] = *(const bf16x8*)&sA[(wm * 64 + i * 16 + fr) * 32 + fq];
#pragma unroll
    for (int j = 0; j < 4; ++j)
      bfr[j] = *(const bf16x8*)&sB[(wn * 64 + j * 16 + fr) * 32 + fq];
#pragma unroll
    for (int i = 0; i < 4; ++i)
#pragma unroll
      for (int j = 0; j < 4; ++j)
        acc[i][j] = __builtin_amdgcn_mfma_f32_16x16x32_bf16(af[i], bfr[j],
                                                            acc[i][j], 0, 0, 0);
    __syncthreads();
  }

  // C/D layout (m89-verified): col = lane&15, row = (lane>>4)*4 + reg
  const int fr = lane & 15, fq4 = (lane >> 4) << 2;
#pragma unroll
  for (int i = 0; i < 4; ++i) {
#pragma unroll
    for (int j = 0; j < 4; ++j) {
      const int rbase = row0 + wm * 64 + i * 16 + fq4;
      const int col = col0 + wn * 64 + j * 16 + fr;
      if constexpr (EPI == 5) {
        // V^T global: (b, h, d, t); rows rbase..rbase+3 are consecutive t
        const int b = rbase >> 11, t = rbase & 2047;
        const int hh = col >> 6, d = col & 63;
        bf16x4 o4 = {(bf16)acc[i][j][0], (bf16)acc[i][j][1],
                     (bf16)acc[i][j][2], (bf16)acc[i][j][3]};
        *(bf16x4*)&((bf16*)Cv)[(((size_t)(b * 16 + hh)) * 64 + d) * 2048 + t] =
            o4;
      } else {
#pragma unroll
        for (int r = 0; r < 4; ++r) {
          const size_t idx = (size_t)(rbase + r) * N + col;
          const float val = acc[i][j][r];
          if constexpr (EPI == 0) {
            ((float*)Cv)[idx] = val;
          } else if constexpr (EPI == 2) {
            ((float*)Cv)[idx] = val + R[idx];
          } else {  // EPI == 3
            ((bf16*)Cv)[idx] =
                (bf16)(0.5f * val * (1.0f + erff(val * 0.7071067811865476f)));
          }
        }
      }
    }
  }
}

template <int EPI, bool SPLIT>
__global__ __launch_bounds__(256) void gemm_bt(
    const bf16* __restrict__ A, const bf16* __restrict__ A2,
    const bf16* __restrict__ B, void* __restrict__ Cv,
    const float* __restrict__ R, int M, int N, int K) {
  __shared__ bf16 smem[8192];
  gemm_body<EPI, SPLIT>(A, A2, B, Cv, R, smem, blockIdx.x * 128,
                        blockIdx.y * 128, M, N, K);
}

// ---------------------------------------------------------------------------
// Merged split-K GEMM for q/k: stages A_hi, A_lo AND B each k-step (B loaded
// ONCE, 32 iters, half the barriers). Split bf16 hi/lo epilogue.
// ---------------------------------------------------------------------------
static __device__ __forceinline__ void gemm_split_merged(
    const bf16* __restrict__ A, const bf16* __restrict__ A2,
    const bf16* __restrict__ B, bf16* __restrict__ Chi, bf16* __restrict__ Clo,
    bf16* smem, float scale, int col0, int row0) {
  constexpr int K = 1024, N = 1024;
  bf16* sAh = smem;         // 128 x 32
  bf16* sAl = smem + 4096;  // 128 x 32
  bf16* sB = smem + 8192;   // 128 x 32
  const int tid = threadIdx.x;
  const int lane = tid & 63;
  const int wid = tid >> 6;
  const int wm = wid >> 1, wn = wid & 1;

  f32x4 acc[4][4];
  const f32x4 fzero = {0.f, 0.f, 0.f, 0.f};
#pragma unroll
  for (int i = 0; i < 4; ++i)
#pragma unroll
    for (int j = 0; j < 4; ++j) acc[i][j] = fzero;

  const int r0 = tid >> 2, c0 = (tid & 3) << 3;
  const int r1 = (256 + tid) >> 2, c1 = ((256 + tid) & 3) << 3;
  bf16* lAh0 = sAh + (wid << 6) * 8;
  bf16* lAh1 = sAh + (256 + (wid << 6)) * 8;
  bf16* lAl0 = sAl + (wid << 6) * 8;
  bf16* lAl1 = sAl + (256 + (wid << 6)) * 8;
  bf16* lB0 = sB + (wid << 6) * 8;
  bf16* lB1 = sB + (256 + (wid << 6)) * 8;

  for (int kt = 0; kt < 32; ++kt) {
    const int k0 = kt << 5;
    async16(A + (size_t)(row0 + r0) * K + k0 + c0, lAh0);
    async16(A + (size_t)(row0 + r1) * K + k0 + c1, lAh1);
    async16(A2 + (size_t)(row0 + r0) * K + k0 + c0, lAl0);
    async16(A2 + (size_t)(row0 + r1) * K + k0 + c1, lAl1);
    async16(B + (size_t)(col0 + r0) * K + k0 + c0, lB0);
    async16(B + (size_t)(col0 + r1) * K + k0 + c1, lB1);
    __syncthreads();
    const int fr = lane & 15, fq = (lane >> 4) << 3;
    bf16x8 ah[4], al[4], bfr[4];
#pragma unroll
    for (int i = 0; i < 4; ++i) {
      ah[i] = *(const bf16x8*)&sAh[(wm * 64 + i * 16 + fr) * 32 + fq];
      al[i] = *(const bf16x8*)&sAl[(wm * 64 + i * 16 + fr) * 32 + fq];
    }
#pragma unroll
    for (int j = 0; j < 4; ++j)
      bfr[j] = *(const bf16x8*)&sB[(wn * 64 + j * 16 + fr) * 32 + fq];
#pragma unroll
    for (int i = 0; i < 4; ++i)
#pragma unroll
      for (int j = 0; j < 4; ++j) {
        acc[i][j] = __builtin_amdgcn_mfma_f32_16x16x32_bf16(ah[i], bfr[j],
                                                            acc[i][j], 0, 0, 0);
        acc[i][j] = __builtin_amdgcn_mfma_f32_16x16x32_bf16(al[i], bfr[j],
                                                            acc[i][j], 0, 0, 0);
      }
    __syncthreads();
  }

  const int fr = lane & 15, fq4 = (lane >> 4) << 2;
#pragma unroll
  for (int i = 0; i < 4; ++i)
#pragma unroll
    for (int j = 0; j < 4; ++j) {
      const int rbase = row0 + wm * 64 + i * 16 + fq4;
      const int col = col0 + wn * 64 + j * 16 + fr;
#pragma unroll
      for (int r = 0; r < 4; ++r) {
        const size_t idx = (size_t)(rbase + r) * N + col;
        const float vs = acc[i][j][r] * scale;
        const bf16 hi = (bf16)vs;
        Chi[idx] = hi;
        Clo[idx] = (bf16)(vs - (float)hi);
      }
    }
}

// Q,K,V fused: grid (24, 32). bx>>3: 0=q (merged split, scaled 1/8),
// 1=k (merged split), 2=v (single-pass bf16 h, transposed store).
// ONE shared buffer (24576 B) for both paths.
__global__ __launch_bounds__(256) void gemm_qkv(
    const bf16* __restrict__ A, const bf16* __restrict__ A2,
    const bf16* __restrict__ Bq, const bf16* __restrict__ Bk,
    const bf16* __restrict__ Bv, bf16* qh, bf16* ql, bf16* kh, bf16* kl,
    bf16* vt) {
  __shared__ bf16 smem[12288];
  const int which = blockIdx.x >> 3;
  const int col0 = (blockIdx.x & 7) * 128, row0 = blockIdx.y * 128;
  if (which == 2) {
    gemm_body<5, false>(A, nullptr, Bv, (void*)vt, nullptr, smem, col0, row0,
                        4096, 1024, 1024);
  } else {
    gemm_split_merged(A, A2, which ? Bk : Bq, which ? kh : qh, which ? kl : ql,
                      smem, which ? 1.0f : 0.125f, col0, row0);
  }
}

// ---------------------------------------------------------------------------
// 128x64-tile GEMM variant for N=1024 outputs (2 blocks/CU instead of 1).
// ---------------------------------------------------------------------------
template <int EPI>
__global__ __launch_bounds__(256) void gemm_bt64(
    const bf16* __restrict__ A, const bf16* __restrict__ B,
    void* __restrict__ Cv, const float* __restrict__ R, int M, int N, int K) {
  __shared__ bf16 sA[128 * 32];
  __shared__ bf16 sB[64 * 32];
  const int col0 = blockIdx.x * 64, row0 = blockIdx.y * 128;
  const int tid = threadIdx.x;
  const int lane = tid & 63;
  const int wid = tid >> 6;
  const int wm = wid >> 1, wn = wid & 1;

  f32x4 acc[4][2];
  const f32x4 fzero = {0.f, 0.f, 0.f, 0.f};
#pragma unroll
  for (int i = 0; i < 4; ++i)
#pragma unroll
    for (int j = 0; j < 2; ++j) acc[i][j] = fzero;

  const int nk = K >> 5;
  const int r0 = tid >> 2, c0 = (tid & 3) << 3;
  const int r1 = (256 + tid) >> 2, c1 = ((256 + tid) & 3) << 3;
  bf16* lA0 = sA + (wid << 6) * 8;
  bf16* lA1 = sA + (256 + (wid << 6)) * 8;
  bf16* lB0 = sB + (wid << 6) * 8;

  for (int kt = 0; kt < nk; ++kt) {
    const int k0 = kt << 5;
    async16(A + (size_t)(row0 + r0) * K + k0 + c0, lA0);
    async16(A + (size_t)(row0 + r1) * K + k0 + c1, lA1);
    async16(B + (size_t)(col0 + r0) * K + k0 + c0, lB0);
    __syncthreads();
    const int fr = lane & 15, fq = (lane >> 4) << 3;
    bf16x8 af[4], bfr[2];
#pragma unroll
    for (int i = 0; i < 4; ++i)
      af[i] = *(const bf16x8*)&sA[(wm * 64 + i * 16 + fr) * 32 + fq];
#pragma unroll
    for (int j = 0; j < 2; ++j)
      bfr[j] = *(const bf16x8*)&sB[(wn * 32 + j * 16 + fr) * 32 + fq];
#pragma unroll
    for (int i = 0; i < 4; ++i)
#pragma unroll
      for (int j = 0; j < 2; ++j)
        acc[i][j] = __builtin_amdgcn_mfma_f32_16x16x32_bf16(af[i], bfr[j],
                                                            acc[i][j], 0, 0, 0);
    __syncthreads();
  }

  const int fr = lane & 15, fq4 = (lane >> 4) << 2;
#pragma unroll
  for (int i = 0; i < 4; ++i) {
#pragma unroll
    for (int j = 0; j < 2; ++j) {
      const int rbase = row0 + wm * 64 + i * 16 + fq4;
      const int col = col0 + wn * 32 + j * 16 + fr;
#pragma unroll
      for (int r = 0; r < 4; ++r) {
        const size_t idx = (size_t)(rbase + r) * N + col;
        const float val = acc[i][j][r];
        if constexpr (EPI == 2) {
          ((float*)Cv)[idx] = val + R[idx];
        } else {
          ((float*)Cv)[idx] = val;
        }
      }
    }
  }
}

// ---------------------------------------------------------------------------
// LayerNorm over D=1024 (f32 input), one block per row.
// ---------------------------------------------------------------------------
template <bool SPLIT>
__global__ __launch_bounds__(256) void ln_kernel(
    const float* __restrict__ x, const float* __restrict__ g,
    const float* __restrict__ b, bf16* __restrict__ hi, bf16* __restrict__ lo) {
  const int row = blockIdx.x;
  const int tid = threadIdx.x;
  const float* xr = x + (size_t)row * 1024;
  float v[4];
  float s1 = 0.f, s2 = 0.f;
#pragma unroll
  for (int j = 0; j < 4; ++j) {
    v[j] = xr[j * 256 + tid];
    s1 += v[j];
    s2 += v[j] * v[j];
  }
#pragma unroll
  for (int off = 1; off < 64; off <<= 1) {
    s1 += __shfl_xor(s1, off);
    s2 += __shfl_xor(s2, off);
  }
  __shared__ float ws1[4], ws2[4];
  const int wid = tid >> 6;
  if ((tid & 63) == 0) {
    ws1[wid] = s1;
    ws2[wid] = s2;
  }
  __syncthreads();
  s1 = ws1[0] + ws1[1] + ws1[2] + ws1[3];
  s2 = ws2[0] + ws2[1] + ws2[2] + ws2[3];
  const float mu = s1 * (1.f / 1024.f);
  const float var = s2 * (1.f / 1024.f) - mu * mu;
  const float rstd = 1.0f / sqrtf(var + 1e-5f);
#pragma unroll
  for (int j = 0; j < 4; ++j) {
    const int cc = j * 256 + tid;
    const float y = (v[j] - mu) * rstd * g[cc] + b[cc];
    const bf16 yh = (bf16)y;
    hi[(size_t)row * 1024 + cc] = yh;
    if constexpr (SPLIT) lo[(size_t)row * 1024 + cc] = (bf16)(y - (float)yh);
  }
}

// ---------------------------------------------------------------------------
// MFMA causal flash attention, 128-query blocks (wave owns 32 queries = two
// 16-row fragments) — same K/V staging serves 2x the queries, V fragments
// shared across sub-tiles: ~47% less LDS b128 traffic per query.
//  - Q fragments from global; next K/V tile register-prefetched
//  - 2 barriers/iter; P region wave-private, reused serially for u=0,1
//  - DPP softmax; LDS 37376 B; grid 512 (2 blocks/CU)
//  - qt mapping pairs long+short blocks per CU (constant ~36 tiles/CU)
//  - plain __launch_bounds__(256): (256,4) caused scratch spill — keep off
// ---------------------------------------------------------------------------
__global__ __launch_bounds__(256) void attn_kernel(
    const bf16* __restrict__ qh_g, const bf16* __restrict__ ql_g,
    const bf16* __restrict__ kh_g, const bf16* __restrict__ kl_g,
    const bf16* __restrict__ vt_g, bf16* __restrict__ out) {
  __shared__ bf16 lds[18688];  // 37376 B
  bf16* Kh = lds;              // 64 x 72
  bf16* Kl = lds + 4608;       // 64 x 72
  bf16* Vt = lds + 9216;       // 64 x 72, rows = dim d, cols = key
  bf16* Ps = lds + 13824;      // 4 waves x 16 x 76 (reused for u=0,1)

  const int bid = blockIdx.x;
  const int g = bid >> 5;
  const int qt = (g < 8) ? (15 - g) : (g - 8);  // long/short pairing
  const int h = bid & 15;
  const int b = (bid >> 4) & 1;
  const int t0 = qt << 7;  // 128-query block
  const int tid = threadIdx.x;
  const int w = tid >> 6;
  const int lane = tid & 63;
  const int c = lane & 15;
  const int quad = lane >> 4;

  // staging map: chunk idx -> (row idx>>3, col8 (idx&7)*8)
  const int r0 = tid >> 3, c0 = (tid & 7) << 3;
  const int r1 = (tid + 256) >> 3, c1 = ((tid + 256) & 7) << 3;

  // Q fragments straight from global (once per block); wave owns 32 queries
  bf16x8 aqh[2][2], aql[2][2];
#pragma unroll
  for (int u = 0; u < 2; ++u) {
    const size_t qrow =
        ((size_t)(b * 2048 + t0 + w * 32 + u * 16 + c)) * 1024 + h * 64 +
        quad * 8;
    aqh[u][0] = *(const bf16x8*)&qh_g[qrow];
    aqh[u][1] = *(const bf16x8*)&qh_g[qrow + 32];
    aql[u][0] = *(const bf16x8*)&ql_g[qrow];
    aql[u][1] = *(const bf16x8*)&ql_g[qrow + 32];
  }

  f32x4 o[2][4];
  const f32x4 fzero = {0.f, 0.f, 0.f, 0.f};
#pragma unroll
  for (int u = 0; u < 2; ++u)
#pragma unroll
    for (int j = 0; j < 4; ++j) o[u][j] = fzero;
  float m_i[2][4], l_i[2][4];
#pragma unroll
  for (int u = 0; u < 2; ++u)
#pragma unroll
    for (int r = 0; r < 4; ++r) {
      m_i[u][r] = -3e38f;
      l_i[u][r] = 0.f;
    }

  const size_t vtb = ((size_t)(b * 16 + h)) * 64 * 2048;  // + d*2048 + t
  const size_t kband = ((size_t)(b * 2048)) * 1024 + h * 64;
  const int nt = 2 * qt + 2;  // 64-key tiles covering keys [0, t0+128)

  bf16x8 gk[6];  // register prefetch of next K/V tile
  {
    gk[0] = *(const bf16x8*)&kh_g[kband + (size_t)r0 * 1024 + c0];
    gk[1] = *(const bf16x8*)&kh_g[kband + (size_t)r1 * 1024 + c1];
    gk[2] = *(const bf16x8*)&kl_g[kband + (size_t)r0 * 1024 + c0];
    gk[3] = *(const bf16x8*)&kl_g[kband + (size_t)r1 * 1024 + c1];
    gk[4] = *(const bf16x8*)&vt_g[vtb + (size_t)r0 * 2048 + c0];
    gk[5] = *(const bf16x8*)&vt_g[vtb + (size_t)r1 * 2048 + c1];
  }

  for (int kt = 0; kt < nt; ++kt) {
    const int kb = kt << 6;
    __syncthreads();  // (A) prev tile's fragment reads done before restage
    *(bf16x8*)&Kh[r0 * 72 + c0] = gk[0];
    *(bf16x8*)&Kh[r1 * 72 + c1] = gk[1];
    *(bf16x8*)&Kl[r0 * 72 + c0] = gk[2];
    *(bf16x8*)&Kl[r1 * 72 + c1] = gk[3];
    *(bf16x8*)&Vt[r0 * 72 + c0] = gk[4];
    *(bf16x8*)&Vt[r1 * 72 + c1] = gk[5];
    __syncthreads();  // (B) staging visible

    if (kt < nt - 1) {  // prefetch next tile; latency hidden behind compute
      const int kb1 = (kt + 1) << 6;
      const size_t kbase = kband + (size_t)kb1 * 1024;
      gk[0] = *(const bf16x8*)&kh_g[kbase + (size_t)r0 * 1024 + c0];
      gk[1] = *(const bf16x8*)&kh_g[kbase + (size_t)r1 * 1024 + c1];
      gk[2] = *(const bf16x8*)&kl_g[kbase + (size_t)r0 * 1024 + c0];
      gk[3] = *(const bf16x8*)&kl_g[kbase + (size_t)r1 * 1024 + c1];
      gk[4] = *(const bf16x8*)&vt_g[vtb + (size_t)r0 * 2048 + kb1 + c0];
      gk[5] = *(const bf16x8*)&vt_g[vtb + (size_t)r1 * 2048 + kb1 + c1];
    }

    bf16x8 bkh[4][2], bkl[4][2], bv[4][2];
#pragma unroll
    for (int j = 0; j < 4; ++j)
#pragma unroll
      for (int s = 0; s < 2; ++s) {
        bkh[j][s] = *(const bf16x8*)&Kh[(j * 16 + c) * 72 + s * 32 + quad * 8];
        bkl[j][s] = *(const bf16x8*)&Kl[(j * 16 + c) * 72 + s * 32 + quad * 8];
        bv[j][s] = *(const bf16x8*)&Vt[(j * 16 + c) * 72 + s * 32 + quad * 8];
      }

    bf16* Pw = Ps + w * 16 * 76;
#pragma unroll
    for (int u = 0; u < 2; ++u) {
      f32x4 s4[4];
#pragma unroll
      for (int j = 0; j < 4; ++j) s4[j] = fzero;
#pragma unroll
      for (int j = 0; j < 4; ++j)
#pragma unroll
        for (int s = 0; s < 2; ++s) {
          s4[j] = __builtin_amdgcn_mfma_f32_16x16x32_bf16(aqh[u][s], bkh[j][s],
                                                          s4[j], 0, 0, 0);
          s4[j] = __builtin_amdgcn_mfma_f32_16x16x32_bf16(aqh[u][s], bkl[j][s],
                                                          s4[j], 0, 0, 0);
          s4[j] = __builtin_amdgcn_mfma_f32_16x16x32_bf16(aql[u][s], bkh[j][s],
                                                          s4[j], 0, 0, 0);
        }

      if (kt >= 2 * qt) {  // diagonal tiles: strict-upper causal mask
        const int qrow0 = t0 + w * 32 + u * 16 + quad * 4;
#pragma unroll
        for (int j = 0; j < 4; ++j)
#pragma unroll
          for (int r = 0; r < 4; ++r)
            if (kb + j * 16 + c > qrow0 + r) s4[j][r] = -3e38f;
      }

      float al[4], p[4][4];
#pragma unroll
      for (int r = 0; r < 4; ++r) {
        float mt = fmaxf(fmaxf(s4[0][r], s4[1][r]), fmaxf(s4[2][r], s4[3][r]));
        mt = rowmax16(mt);  // DPP row reduce
        const float mn = fmaxf(m_i[u][r], mt);
        al[r] = __expf(m_i[u][r] - mn);
        float ps = 0.f;
#pragma unroll
        for (int j = 0; j < 4; ++j) {
          p[r][j] = __expf(s4[j][r] - mn);
          ps += p[r][j];
        }
        ps = rowsum16(ps);  // DPP row reduce
        l_i[u][r] = l_i[u][r] * al[r] + ps;
        m_i[u][r] = mn;
#pragma unroll
        for (int j = 0; j < 4; ++j) o[u][j][r] *= al[r];
      }

      // P -> wave-private region, stride 76 (intra-wave RAW only; in-order DS)
#pragma unroll
      for (int r = 0; r < 4; ++r)
#pragma unroll
        for (int j = 0; j < 4; ++j)
          Pw[(quad * 4 + r) * 76 + j * 16 + c] = (bf16)p[r][j];

      bf16x8 ap[2];
#pragma unroll
      for (int s = 0; s < 2; ++s)
        ap[s] = *(const bf16x8*)&Pw[c * 76 + s * 32 + quad * 8];
#pragma unroll
      for (int j = 0; j < 4; ++j)
#pragma unroll
        for (int s = 0; s < 2; ++s)
          o[u][j] = __builtin_amdgcn_mfma_f32_16x16x32_bf16(ap[s], bv[j][s],
                                                            o[u][j], 0, 0, 0);
    }
  }

#pragma unroll
  for (int u = 0; u < 2; ++u)
#pragma unroll
    for (int r = 0; r < 4; ++r) {
      const float inv = 1.0f / l_i[u][r];
#pragma unroll
      for (int j = 0; j < 4; ++j) {
        const size_t oi =
            ((size_t)(b * 2048 + t0 + w * 32 + u * 16 + quad * 4 + r)) * 1024 +
            h * 64 + j * 16 + c;
        out[oi] = (bf16)(o[u][j][r] * inv);
      }
    }
}

// ---------------------------------------------------------------------------
// Workspace plan (80 MiB peak; >104 MiB previously corrupted harness memory):
//   [ 0, 8)   Wq|Wk|Wv|Wo bf16
//   [ 8,24)   h_hi|h_lo  -> (after gemm_qkv) Wf1_b|Wf2_b   (cvt2 overwrite)
//   [24,40)   qh|ql      -> (after attn)   x1 (f32)
//   [40,72)   kh|kl|vt|attnout -> (after k4) ff (bf16 4096x4096)
//   [72,80)   h2
// ---------------------------------------------------------------------------
extern "C" void kernel_launch(void* const* d_in, const int* in_sizes, int n_in,
                              void* d_out, int out_size, void* d_ws,
                              size_t ws_size, hipStream_t stream) {
  const float* x = (const float*)d_in[0];
  const float* g1 = (const float*)d_in[2];
  const float* b1 = (const float*)d_in[3];
  const float* g2 = (const float*)d_in[4];
  const float* b2 = (const float*)d_in[5];
  const float* Wq = (const float*)d_in[6];
  const float* Wk = (const float*)d_in[7];
  const float* Wv = (const float*)d_in[8];
  const float* Wo = (const float*)d_in[9];
  const float* Wf1 = (const float*)d_in[10];
  const float* Wf2 = (const float*)d_in[11];
  char* ws = (char*)d_ws;
  const size_t MB = 1024 * 1024;
  const size_t M1 = 1u << 20;
  bf16* Wq_b = (bf16*)ws;
  bf16* Wk_b = Wq_b + 1 * M1;
  bf16* Wv_b = Wq_b + 2 * M1;
  bf16* Wo_b = Wq_b + 3 * M1;
  bf16* h_hi = (bf16*)(ws + 8 * MB);
  bf16* h_lo = (bf16*)(ws + 16 * MB);
  bf16* Wf1_b = h_hi;  // alias: h dead after gemm_qkv; cvt2 fills before k6
  bf16* Wf2_b = h_lo;
  bf16* qh = (bf16*)(ws + 24 * MB);
  bf16* ql = (bf16*)(ws + 32 * MB);
  bf16* kh = (bf16*)(ws + 40 * MB);
  bf16* kl = (bf16*)(ws + 48 * MB);
  bf16* vt = (bf16*)(ws + 56 * MB);
  bf16* attnout = (bf16*)(ws + 64 * MB);
  float* x1 = (float*)qh;  // alias: qh/ql dead after attn
  bf16* h2 = (bf16*)(ws + 72 * MB);
  bf16* ff = kh;  // alias: kh/kl/vt/attnout dead after k4
  float* outp = (float*)d_out;

  // 0) attention-path weights f32 -> bf16 (exact for ternary)
  cvt4<<<4096, 256, 0, stream>>>(Wq, Wk, Wv, Wo, Wq_b);
  // 1) LN1 -> split bf16 hi/lo
  ln_kernel<true><<<4096, 256, 0, stream>>>(x, g1, b1, h_hi, h_lo);
  // 2) Q,K (merged split bf16, q pre-scaled 1/8) + V^T (single-pass) fused
  gemm_qkv<<<dim3(24, 32), 256, 0, stream>>>(h_hi, h_lo, Wq_b, Wk_b, Wv_b, qh,
                                             ql, kh, kl, vt);
  // 2.5) h is dead now: convert FF weights into its slot
  cvt2<<<8192, 256, 0, stream>>>(Wf1, Wf2, Wf1_b);
  // 3) MFMA causal flash attention (128-query blocks) -> bf16 (B,T,1024)
  attn_kernel<<<512, 256, 0, stream>>>(qh, ql, kh, kl, vt, attnout);
  // 4) x1 = x + attnout @ Wo^T   (f32; overwrites dead qh/ql) — 64N tiles
  gemm_bt64<2><<<dim3(16, 32), 256, 0, stream>>>(attnout, Wo_b, (void*)x1, x,
                                                 4096, 1024, 1024);
  // 5) LN2 -> h2 (bf16)
  ln_kernel<false><<<4096, 256, 0, stream>>>(x1, g2, b2, h2, nullptr);
  // 6) ff = gelu(h2 @ Wff1^T)  (bf16; overwrites dead kh/kl/vt/attnout)
  gemm_bt<3, false><<<dim3(32, 32), 256, 0, stream>>>(
      h2, nullptr, Wf1_b, (void*)ff, nullptr, 4096, 4096, 1024);
  // 7) out = x1 + ff @ Wff2^T  (f32) — 64N tiles
  gemm_bt64<2><<<dim3(16, 32), 256, 0, stream>>>(ff, Wf2_b, (void*)outp, x1,
                                                 4096, 1024, 4096);
}

// Round 10
// 456.277 us; speedup vs baseline: 1.0701x; 1.0701x over previous
//
#include <hip/hip_runtime.h>

typedef __bf16 bf16;
typedef bf16 bf16x8 __attribute__((ext_vector_type(8)));
typedef bf16 bf16x4 __attribute__((ext_vector_type(4)));
typedef float f32x4 __attribute__((ext_vector_type(4)));

// ---------------------------------------------------------------------------
// async global->LDS 16B copy (wave-uniform LDS base + lane*16 placement)
// ---------------------------------------------------------------------------
static __device__ __forceinline__ void async16(const void* g, void* l) {
  __builtin_amdgcn_global_load_lds((__attribute__((address_space(1))) void*)g,
                                   (__attribute__((address_space(3))) void*)l,
                                   16, 0, 0);
}

// DPP row_ror:N within 16-lane rows (VALU-only cross-lane; no LDS pipe).
template <int N>
static __device__ __forceinline__ float ror16(float x) {
  const int y =
      __builtin_amdgcn_update_dpp(0, __float_as_int(x), 0x120 | N, 0xf, 0xf, true);
  return __int_as_float(y);
}
static __device__ __forceinline__ float rowmax16(float x) {
  x = fmaxf(x, ror16<8>(x));
  x = fmaxf(x, ror16<4>(x));
  x = fmaxf(x, ror16<2>(x));
  x = fmaxf(x, ror16<1>(x));
  return x;
}
static __device__ __forceinline__ float rowsum16(float x) {
  x += ror16<8>(x);
  x += ror16<4>(x);
  x += ror16<2>(x);
  x += ror16<1>(x);
  return x;
}

// ---------------------------------------------------------------------------
// LN1 (split bf16 hi/lo) fused with cvt4 (attention weights f32->bf16).
// blocks [0,4096): LN rows; blocks [4096,8192): weight conversion chunks.
// ---------------------------------------------------------------------------
__global__ __launch_bounds__(256) void ln1_cvt4(
    const float* __restrict__ x, const float* __restrict__ g,
    const float* __restrict__ b, bf16* __restrict__ hi, bf16* __restrict__ lo,
    const float* __restrict__ Wq, const float* __restrict__ Wk,
    const float* __restrict__ Wv, const float* __restrict__ Wo,
    bf16* __restrict__ wdst) {
  const int tid = threadIdx.x;
  if (blockIdx.x >= 4096) {  // cvt4 path
    const size_t i = ((size_t)(blockIdx.x - 4096) * 256 + tid) * 4;
    const size_t M1 = 1u << 20;
    const float* src = (i < M1) ? Wq : (i < 2 * M1) ? Wk : (i < 3 * M1) ? Wv : Wo;
    const size_t off = i & (M1 - 1);
    const float4 v = *(const float4*)(src + off);
    bf16x4 o = {(bf16)v.x, (bf16)v.y, (bf16)v.z, (bf16)v.w};
    *(bf16x4*)(wdst + i) = o;
    return;
  }
  const int row = blockIdx.x;
  const float* xr = x + (size_t)row * 1024;
  float v[4];
  float s1 = 0.f, s2 = 0.f;
#pragma unroll
  for (int j = 0; j < 4; ++j) {
    v[j] = xr[j * 256 + tid];
    s1 += v[j];
    s2 += v[j] * v[j];
  }
#pragma unroll
  for (int off = 1; off < 64; off <<= 1) {
    s1 += __shfl_xor(s1, off);
    s2 += __shfl_xor(s2, off);
  }
  __shared__ float ws1[4], ws2[4];
  const int wid = tid >> 6;
  if ((tid & 63) == 0) {
    ws1[wid] = s1;
    ws2[wid] = s2;
  }
  __syncthreads();
  s1 = ws1[0] + ws1[1] + ws1[2] + ws1[3];
  s2 = ws2[0] + ws2[1] + ws2[2] + ws2[3];
  const float mu = s1 * (1.f / 1024.f);
  const float var = s2 * (1.f / 1024.f) - mu * mu;
  const float rstd = 1.0f / sqrtf(var + 1e-5f);
#pragma unroll
  for (int j = 0; j < 4; ++j) {
    const int cc = j * 256 + tid;
    const float y = (v[j] - mu) * rstd * g[cc] + b[cc];
    const bf16 yh = (bf16)y;
    hi[(size_t)row * 1024 + cc] = yh;
    lo[(size_t)row * 1024 + cc] = (bf16)(y - (float)yh);
  }
}

// ---------------------------------------------------------------------------
// LayerNorm over D=1024 (f32 input), one block per row (non-split).
// ---------------------------------------------------------------------------
__global__ __launch_bounds__(256) void ln_kernel(
    const float* __restrict__ x, const float* __restrict__ g,
    const float* __restrict__ b, bf16* __restrict__ hi) {
  const int row = blockIdx.x;
  const int tid = threadIdx.x;
  const float* xr = x + (size_t)row * 1024;
  float v[4];
  float s1 = 0.f, s2 = 0.f;
#pragma unroll
  for (int j = 0; j < 4; ++j) {
    v[j] = xr[j * 256 + tid];
    s1 += v[j];
    s2 += v[j] * v[j];
  }
#pragma unroll
  for (int off = 1; off < 64; off <<= 1) {
    s1 += __shfl_xor(s1, off);
    s2 += __shfl_xor(s2, off);
  }
  __shared__ float ws1[4], ws2[4];
  const int wid = tid >> 6;
  if ((tid & 63) == 0) {
    ws1[wid] = s1;
    ws2[wid] = s2;
  }
  __syncthreads();
  s1 = ws1[0] + ws1[1] + ws1[2] + ws1[3];
  s2 = ws2[0] + ws2[1] + ws2[2] + ws2[3];
  const float mu = s1 * (1.f / 1024.f);
  const float var = s2 * (1.f / 1024.f) - mu * mu;
  const float rstd = 1.0f / sqrtf(var + 1e-5f);
#pragma unroll
  for (int j = 0; j < 4; ++j) {
    const int cc = j * 256 + tid;
    const float y = (v[j] - mu) * rstd * g[cc] + b[cc];
    hi[(size_t)row * 1024 + cc] = (bf16)y;
  }
}

// ---------------------------------------------------------------------------
// GEMM: C[M,N] = A[M,K] * B[N,K]^T   (m97 structure)
// EPI: 0 = f32 store, 2 = f32(acc + R[f32]), 3 = bf16 gelu(acc),
//      5 = bf16 store transposed to V^T global layout (b,h,d,t)
// smem: caller-provided (>= 8192 bf16).
// ---------------------------------------------------------------------------
template <int EPI, bool SPLIT>
static __device__ __forceinline__ void gemm_body(
    const bf16* __restrict__ A, const bf16* __restrict__ A2,
    const bf16* __restrict__ B, void* __restrict__ Cv,
    const float* __restrict__ R, bf16* smem, int col0, int row0, int M, int N,
    int K) {
  bf16* sA = smem;         // 128 x 32
  bf16* sB = smem + 4096;  // 128 x 32
  const int tid = threadIdx.x;
  const int lane = tid & 63;
  const int wid = tid >> 6;
  const int wm = wid >> 1, wn = wid & 1;

  f32x4 acc[4][4];
  const f32x4 fzero = {0.f, 0.f, 0.f, 0.f};
#pragma unroll
  for (int i = 0; i < 4; ++i)
#pragma unroll
    for (int j = 0; j < 4; ++j) acc[i][j] = fzero;

  const int nk = K >> 5;
  const int total = SPLIT ? (nk << 1) : nk;
  const int r0 = tid >> 2, c0 = (tid & 3) << 3;
  const int r1 = (256 + tid) >> 2, c1 = ((256 + tid) & 3) << 3;
  bf16* lA0 = sA + (wid << 6) * 8;  // wave-uniform LDS bases
  bf16* lA1 = sA + (256 + (wid << 6)) * 8;
  bf16* lB0 = sB + (wid << 6) * 8;
  bf16* lB1 = sB + (256 + (wid << 6)) * 8;

  for (int kt = 0; kt < total; ++kt) {
    const int kk = (kt < nk) ? kt : kt - nk;
    const bf16* Ap = (SPLIT && kt >= nk) ? A2 : A;
    const int k0 = kk << 5;
    async16(Ap + (size_t)(row0 + r0) * K + k0 + c0, lA0);
    async16(Ap + (size_t)(row0 + r1) * K + k0 + c1, lA1);
    async16(B + (size_t)(col0 + r0) * K + k0 + c0, lB0);
    async16(B + (size_t)(col0 + r1) * K + k0 + c1, lB1);
    __syncthreads();
    const int fr = lane & 15, fq = (lane >> 4) << 3;
    bf16x8 af[4], bfr[4];
#pragma unroll
    for (int i = 0; i < 4; ++i)
      af[i] = *(const bf16x8*)&sA[(wm * 64 + i * 16 + fr) * 32 + fq];
#pragma unroll
    for (int j = 0; j < 4; ++j)
      bfr[j] = *(const bf16x8*)&sB[(wn * 64 + j * 16 + fr) * 32 + fq];
#pragma unroll
    for (int i = 0; i < 4; ++i)
#pragma unroll
      for (int j = 0; j < 4; ++j)
        acc[i][j] = __builtin_amdgcn_mfma_f32_16x16x32_bf16(af[i], bfr[j],
                                                            acc[i][j], 0, 0, 0);
    __syncthreads();
  }

  // C/D layout (m89-verified): col = lane&15, row = (lane>>4)*4 + reg
  const int fr = lane & 15, fq4 = (lane >> 4) << 2;
#pragma unroll
  for (int i = 0; i < 4; ++i) {
#pragma unroll
    for (int j = 0; j < 4; ++j) {
      const int rbase = row0 + wm * 64 + i * 16 + fq4;
      const int col = col0 + wn * 64 + j * 16 + fr;
      if constexpr (EPI == 5) {
        const int b = rbase >> 11, t = rbase & 2047;
        const int hh = col >> 6, d = col & 63;
        bf16x4 o4 = {(bf16)acc[i][j][0], (bf16)acc[i][j][1],
                     (bf16)acc[i][j][2], (bf16)acc[i][j][3]};
        *(bf16x4*)&((bf16*)Cv)[(((size_t)(b * 16 + hh)) * 64 + d) * 2048 + t] =
            o4;
      } else {
#pragma unroll
        for (int r = 0; r < 4; ++r) {
          const size_t idx = (size_t)(rbase + r) * N + col;
          const float val = acc[i][j][r];
          if constexpr (EPI == 0) {
            ((float*)Cv)[idx] = val;
          } else if constexpr (EPI == 2) {
            ((float*)Cv)[idx] = val + R[idx];
          } else {  // EPI == 3
            ((bf16*)Cv)[idx] =
                (bf16)(0.5f * val * (1.0f + erff(val * 0.7071067811865476f)));
          }
        }
      }
    }
  }
}

template <int EPI, bool SPLIT>
__global__ __launch_bounds__(256) void gemm_bt(
    const bf16* __restrict__ A, const bf16* __restrict__ A2,
    const bf16* __restrict__ B, void* __restrict__ Cv,
    const float* __restrict__ R, int M, int N, int K) {
  __shared__ bf16 smem[8192];
  gemm_body<EPI, SPLIT>(A, A2, B, Cv, R, smem, blockIdx.x * 128,
                        blockIdx.y * 128, M, N, K);
}

// ---------------------------------------------------------------------------
// Merged split-K GEMM for q/k: stages A_hi, A_lo AND B each k-step (B loaded
// ONCE, 32 iters, half the barriers). Split bf16 hi/lo epilogue.
// ---------------------------------------------------------------------------
static __device__ __forceinline__ void gemm_split_merged(
    const bf16* __restrict__ A, const bf16* __restrict__ A2,
    const bf16* __restrict__ B, bf16* __restrict__ Chi, bf16* __restrict__ Clo,
    bf16* smem, float scale, int col0, int row0) {
  constexpr int K = 1024, N = 1024;
  bf16* sAh = smem;         // 128 x 32
  bf16* sAl = smem + 4096;  // 128 x 32
  bf16* sB = smem + 8192;   // 128 x 32
  const int tid = threadIdx.x;
  const int lane = tid & 63;
  const int wid = tid >> 6;
  const int wm = wid >> 1, wn = wid & 1;

  f32x4 acc[4][4];
  const f32x4 fzero = {0.f, 0.f, 0.f, 0.f};
#pragma unroll
  for (int i = 0; i < 4; ++i)
#pragma unroll
    for (int j = 0; j < 4; ++j) acc[i][j] = fzero;

  const int r0 = tid >> 2, c0 = (tid & 3) << 3;
  const int r1 = (256 + tid) >> 2, c1 = ((256 + tid) & 3) << 3;
  bf16* lAh0 = sAh + (wid << 6) * 8;
  bf16* lAh1 = sAh + (256 + (wid << 6)) * 8;
  bf16* lAl0 = sAl + (wid << 6) * 8;
  bf16* lAl1 = sAl + (256 + (wid << 6)) * 8;
  bf16* lB0 = sB + (wid << 6) * 8;
  bf16* lB1 = sB + (256 + (wid << 6)) * 8;

  for (int kt = 0; kt < 32; ++kt) {
    const int k0 = kt << 5;
    async16(A + (size_t)(row0 + r0) * K + k0 + c0, lAh0);
    async16(A + (size_t)(row0 + r1) * K + k0 + c1, lAh1);
    async16(A2 + (size_t)(row0 + r0) * K + k0 + c0, lAl0);
    async16(A2 + (size_t)(row0 + r1) * K + k0 + c1, lAl1);
    async16(B + (size_t)(col0 + r0) * K + k0 + c0, lB0);
    async16(B + (size_t)(col0 + r1) * K + k0 + c1, lB1);
    __syncthreads();
    const int fr = lane & 15, fq = (lane >> 4) << 3;
    bf16x8 ah[4], al[4], bfr[4];
#pragma unroll
    for (int i = 0; i < 4; ++i) {
      ah[i] = *(const bf16x8*)&sAh[(wm * 64 + i * 16 + fr) * 32 + fq];
      al[i] = *(const bf16x8*)&sAl[(wm * 64 + i * 16 + fr) * 32 + fq];
    }
#pragma unroll
    for (int j = 0; j < 4; ++j)
      bfr[j] = *(const bf16x8*)&sB[(wn * 64 + j * 16 + fr) * 32 + fq];
#pragma unroll
    for (int i = 0; i < 4; ++i)
#pragma unroll
      for (int j = 0; j < 4; ++j) {
        acc[i][j] = __builtin_amdgcn_mfma_f32_16x16x32_bf16(ah[i], bfr[j],
                                                            acc[i][j], 0, 0, 0);
        acc[i][j] = __builtin_amdgcn_mfma_f32_16x16x32_bf16(al[i], bfr[j],
                                                            acc[i][j], 0, 0, 0);
      }
    __syncthreads();
  }

  const int fr = lane & 15, fq4 = (lane >> 4) << 2;
#pragma unroll
  for (int i = 0; i < 4; ++i)
#pragma unroll
    for (int j = 0; j < 4; ++j) {
      const int rbase = row0 + wm * 64 + i * 16 + fq4;
      const int col = col0 + wn * 64 + j * 16 + fr;
#pragma unroll
      for (int r = 0; r < 4; ++r) {
        const size_t idx = (size_t)(rbase + r) * N + col;
        const float vs = acc[i][j][r] * scale;
        const bf16 hi = (bf16)vs;
        Chi[idx] = hi;
        Clo[idx] = (bf16)(vs - (float)hi);
      }
    }
}

// Q,K,V fused: grid (24, 32). bx>>3: 0=q (merged split, scaled 1/8),
// 1=k (merged split), 2=v (single-pass bf16 h, transposed store).
__global__ __launch_bounds__(256) void gemm_qkv(
    const bf16* __restrict__ A, const bf16* __restrict__ A2,
    const bf16* __restrict__ Bq, const bf16* __restrict__ Bk,
    const bf16* __restrict__ Bv, bf16* qh, bf16* ql, bf16* kh, bf16* kl,
    bf16* vt) {
  __shared__ bf16 smem[12288];
  const int which = blockIdx.x >> 3;
  const int col0 = (blockIdx.x & 7) * 128, row0 = blockIdx.y * 128;
  if (which == 2) {
    gemm_body<5, false>(A, nullptr, Bv, (void*)vt, nullptr, smem, col0, row0,
                        4096, 1024, 1024);
  } else {
    gemm_split_merged(A, A2, which ? Bk : Bq, which ? kh : qh, which ? kl : ql,
                      smem, which ? 1.0f : 0.125f, col0, row0);
  }
}

// ---------------------------------------------------------------------------
// 128x64-tile GEMM variant for N=1024 outputs (2 blocks/CU instead of 1).
// ---------------------------------------------------------------------------
template <int EPI>
__global__ __launch_bounds__(256) void gemm_bt64(
    const bf16* __restrict__ A, const bf16* __restrict__ B,
    void* __restrict__ Cv, const float* __restrict__ R, int M, int N, int K) {
  __shared__ bf16 sA[128 * 32];
  __shared__ bf16 sB[64 * 32];
  const int col0 = blockIdx.x * 64, row0 = blockIdx.y * 128;
  const int tid = threadIdx.x;
  const int lane = tid & 63;
  const int wid = tid >> 6;
  const int wm = wid >> 1, wn = wid & 1;

  f32x4 acc[4][2];
  const f32x4 fzero = {0.f, 0.f, 0.f, 0.f};
#pragma unroll
  for (int i = 0; i < 4; ++i)
#pragma unroll
    for (int j = 0; j < 2; ++j) acc[i][j] = fzero;

  const int nk = K >> 5;
  const int r0 = tid >> 2, c0 = (tid & 3) << 3;
  const int r1 = (256 + tid) >> 2, c1 = ((256 + tid) & 3) << 3;
  bf16* lA0 = sA + (wid << 6) * 8;
  bf16* lA1 = sA + (256 + (wid << 6)) * 8;
  bf16* lB0 = sB + (wid << 6) * 8;

  for (int kt = 0; kt < nk; ++kt) {
    const int k0 = kt << 5;
    async16(A + (size_t)(row0 + r0) * K + k0 + c0, lA0);
    async16(A + (size_t)(row0 + r1) * K + k0 + c1, lA1);
    async16(B + (size_t)(col0 + r0) * K + k0 + c0, lB0);
    __syncthreads();
    const int fr = lane & 15, fq = (lane >> 4) << 3;
    bf16x8 af[4], bfr[2];
#pragma unroll
    for (int i = 0; i < 4; ++i)
      af[i] = *(const bf16x8*)&sA[(wm * 64 + i * 16 + fr) * 32 + fq];
#pragma unroll
    for (int j = 0; j < 2; ++j)
      bfr[j] = *(const bf16x8*)&sB[(wn * 32 + j * 16 + fr) * 32 + fq];
#pragma unroll
    for (int i = 0; i < 4; ++i)
#pragma unroll
      for (int j = 0; j < 2; ++j)
        acc[i][j] = __builtin_amdgcn_mfma_f32_16x16x32_bf16(af[i], bfr[j],
                                                            acc[i][j], 0, 0, 0);
    __syncthreads();
  }

  const int fr = lane & 15, fq4 = (lane >> 4) << 2;
#pragma unroll
  for (int i = 0; i < 4; ++i) {
#pragma unroll
    for (int j = 0; j < 2; ++j) {
      const int rbase = row0 + wm * 64 + i * 16 + fq4;
      const int col = col0 + wn * 32 + j * 16 + fr;
#pragma unroll
      for (int r = 0; r < 4; ++r) {
        const size_t idx = (size_t)(rbase + r) * N + col;
        const float val = acc[i][j][r];
        if constexpr (EPI == 2) {
          ((float*)Cv)[idx] = val + R[idx];
        } else {
          ((float*)Cv)[idx] = val;
        }
      }
    }
  }
}

// ---------------------------------------------------------------------------
// MFMA causal flash attention (round-8 champion: 64-query blocks, 88 VGPR)
// fused with cvt2 (FF weights f32->bf16) in blocks [1024, 9216) — the copy
// blocks backfill CUs during attn's causal tail.
//  - Q fragments from global; next K/V tile register-prefetched
//  - 2 barriers/iter; P tile wave-private (stride 76, intra-wave RAW only)
//  - DPP softmax (no LDS-pipe bpermutes); LDS 37376 B -> 4 blocks/CU
//  - plain __launch_bounds__(256): (256,4) caused scratch spill — keep off
//  - 128-query variant (r9) regressed: VGPR 148 -> occupancy 8.8% — keep 64q
// ---------------------------------------------------------------------------
__global__ __launch_bounds__(256) void attn_cvt2(
    const bf16* __restrict__ qh_g, const bf16* __restrict__ ql_g,
    const bf16* __restrict__ kh_g, const bf16* __restrict__ kl_g,
    const bf16* __restrict__ vt_g, bf16* __restrict__ out,
    const float* __restrict__ Wf1, const float* __restrict__ Wf2,
    bf16* __restrict__ wdst) {
  __shared__ bf16 lds[18688];  // 37376 B
  const int tid = threadIdx.x;
  if (blockIdx.x >= 1024) {  // cvt2 path
    const size_t i = ((size_t)(blockIdx.x - 1024) * 256 + tid) * 4;
    const size_t M4 = 4u << 20;
    const float* src = (i < M4) ? Wf1 : Wf2;
    const size_t off = (i < M4) ? i : i - M4;
    const float4 v = *(const float4*)(src + off);
    bf16x4 o4 = {(bf16)v.x, (bf16)v.y, (bf16)v.z, (bf16)v.w};
    *(bf16x4*)(wdst + i) = o4;
    return;
  }
  bf16* Kh = lds;          // 64 x 72
  bf16* Kl = lds + 4608;   // 64 x 72
  bf16* Vt = lds + 9216;   // 64 x 72, rows = dim d, cols = key
  bf16* Ps = lds + 13824;  // 4 waves x 16 x 76 (wave-private)

  const int bid = blockIdx.x;
  const int qt = 31 - (bid >> 5);  // long blocks first
  const int h = bid & 15;
  const int b = (bid >> 4) & 1;
  const int t0 = qt << 6;
  const int w = tid >> 6;
  const int lane = tid & 63;
  const int c = lane & 15;
  const int quad = lane >> 4;

  const int r0 = tid >> 3, c0 = (tid & 7) << 3;
  const int r1 = (tid + 256) >> 3, c1 = ((tid + 256) & 7) << 3;

  // Q fragments straight from global (once per block)
  const size_t qrow =
      ((size_t)(b * 2048 + t0 + w * 16 + c)) * 1024 + h * 64 + quad * 8;
  bf16x8 aqh[2], aql[2];
  aqh[0] = *(const bf16x8*)&qh_g[qrow];
  aqh[1] = *(const bf16x8*)&qh_g[qrow + 32];
  aql[0] = *(const bf16x8*)&ql_g[qrow];
  aql[1] = *(const bf16x8*)&ql_g[qrow + 32];

  f32x4 o[4];
  const f32x4 fzero = {0.f, 0.f, 0.f, 0.f};
#pragma unroll
  for (int j = 0; j < 4; ++j) o[j] = fzero;
  float m_i[4] = {-3e38f, -3e38f, -3e38f, -3e38f};
  float l_i[4] = {0.f, 0.f, 0.f, 0.f};

  const size_t vtb = ((size_t)(b * 16 + h)) * 64 * 2048;  // + d*2048 + t
  const size_t kband = ((size_t)(b * 2048)) * 1024 + h * 64;

  bf16x8 gk[6];  // register prefetch of next K/V tile
  {
    gk[0] = *(const bf16x8*)&kh_g[kband + (size_t)r0 * 1024 + c0];
    gk[1] = *(const bf16x8*)&kh_g[kband + (size_t)r1 * 1024 + c1];
    gk[2] = *(const bf16x8*)&kl_g[kband + (size_t)r0 * 1024 + c0];
    gk[3] = *(const bf16x8*)&kl_g[kband + (size_t)r1 * 1024 + c1];
    gk[4] = *(const bf16x8*)&vt_g[vtb + (size_t)r0 * 2048 + c0];
    gk[5] = *(const bf16x8*)&vt_g[vtb + (size_t)r1 * 2048 + c1];
  }

  for (int kt = 0; kt <= qt; ++kt) {
    __syncthreads();  // (A) prev tile's fragment reads done before restage
    *(bf16x8*)&Kh[r0 * 72 + c0] = gk[0];
    *(bf16x8*)&Kh[r1 * 72 + c1] = gk[1];
    *(bf16x8*)&Kl[r0 * 72 + c0] = gk[2];
    *(bf16x8*)&Kl[r1 * 72 + c1] = gk[3];
    *(bf16x8*)&Vt[r0 * 72 + c0] = gk[4];
    *(bf16x8*)&Vt[r1 * 72 + c1] = gk[5];
    __syncthreads();  // (B) staging visible

    if (kt < qt) {  // prefetch next tile; latency hidden behind compute
      const int kb1 = (kt + 1) << 6;
      const size_t kbase = kband + (size_t)kb1 * 1024;
      gk[0] = *(const bf16x8*)&kh_g[kbase + (size_t)r0 * 1024 + c0];
      gk[1] = *(const bf16x8*)&kh_g[kbase + (size_t)r1 * 1024 + c1];
      gk[2] = *(const bf16x8*)&kl_g[kbase + (size_t)r0 * 1024 + c0];
      gk[3] = *(const bf16x8*)&kl_g[kbase + (size_t)r1 * 1024 + c1];
      gk[4] = *(const bf16x8*)&vt_g[vtb + (size_t)r0 * 2048 + kb1 + c0];
      gk[5] = *(const bf16x8*)&vt_g[vtb + (size_t)r1 * 2048 + kb1 + c1];
    }

    bf16x8 bkh[4][2], bkl[4][2];
#pragma unroll
    for (int j = 0; j < 4; ++j)
#pragma unroll
      for (int s = 0; s < 2; ++s) {
        bkh[j][s] = *(const bf16x8*)&Kh[(j * 16 + c) * 72 + s * 32 + quad * 8];
        bkl[j][s] = *(const bf16x8*)&Kl[(j * 16 + c) * 72 + s * 32 + quad * 8];
      }

    f32x4 s4[4];
#pragma unroll
    for (int j = 0; j < 4; ++j) s4[j] = fzero;
#pragma unroll
    for (int j = 0; j < 4; ++j)
#pragma unroll
      for (int s = 0; s < 2; ++s) {
        s4[j] = __builtin_amdgcn_mfma_f32_16x16x32_bf16(aqh[s], bkh[j][s], s4[j], 0, 0, 0);
        s4[j] = __builtin_amdgcn_mfma_f32_16x16x32_bf16(aqh[s], bkl[j][s], s4[j], 0, 0, 0);
        s4[j] = __builtin_amdgcn_mfma_f32_16x16x32_bf16(aql[s], bkh[j][s], s4[j], 0, 0, 0);
      }

    if (kt == qt) {  // diagonal tile: strict-upper mask (t0 == kb)
#pragma unroll
      for (int j = 0; j < 4; ++j)
#pragma unroll
        for (int r = 0; r < 4; ++r)
          if (j * 16 + c > w * 16 + quad * 4 + r) s4[j][r] = -3e38f;
    }

    float al[4], p[4][4];
#pragma unroll
    for (int r = 0; r < 4; ++r) {
      float mt = fmaxf(fmaxf(s4[0][r], s4[1][r]), fmaxf(s4[2][r], s4[3][r]));
      mt = rowmax16(mt);  // DPP row reduce
      const float mn = fmaxf(m_i[r], mt);
      al[r] = __expf(m_i[r] - mn);
      float ps = 0.f;
#pragma unroll
      for (int j = 0; j < 4; ++j) {
        p[r][j] = __expf(s4[j][r] - mn);
        ps += p[r][j];
      }
      ps = rowsum16(ps);  // DPP row reduce
      l_i[r] = l_i[r] * al[r] + ps;
      m_i[r] = mn;
#pragma unroll
      for (int j = 0; j < 4; ++j) o[j][r] *= al[r];
    }

    // P -> wave-private region, stride 76 (conflict-free; intra-wave RAW only)
    bf16* Pw = Ps + w * 16 * 76;
#pragma unroll
    for (int r = 0; r < 4; ++r)
#pragma unroll
      for (int j = 0; j < 4; ++j)
        Pw[(quad * 4 + r) * 76 + j * 16 + c] = (bf16)p[r][j];

    bf16x8 ap[2], bv[4][2];
#pragma unroll
    for (int s = 0; s < 2; ++s)
      ap[s] = *(const bf16x8*)&Pw[c * 76 + s * 32 + quad * 8];
#pragma unroll
    for (int j = 0; j < 4; ++j)
#pragma unroll
      for (int s = 0; s < 2; ++s)
        bv[j][s] = *(const bf16x8*)&Vt[(j * 16 + c) * 72 + s * 32 + quad * 8];
#pragma unroll
    for (int j = 0; j < 4; ++j)
#pragma unroll
      for (int s = 0; s < 2; ++s)
        o[j] = __builtin_amdgcn_mfma_f32_16x16x32_bf16(ap[s], bv[j][s], o[j], 0, 0, 0);
  }

#pragma unroll
  for (int r = 0; r < 4; ++r) {
    const float inv = 1.0f / l_i[r];
#pragma unroll
    for (int j = 0; j < 4; ++j) {
      const size_t oi =
          ((size_t)(b * 2048 + t0 + w * 16 + quad * 4 + r)) * 1024 + h * 64 +
          j * 16 + c;
      out[oi] = (bf16)(o[j][r] * inv);
    }
  }
}

// ---------------------------------------------------------------------------
// Workspace plan (80 MiB peak; >104 MiB previously corrupted harness memory):
//   [ 0, 8)   Wq|Wk|Wv|Wo bf16
//   [ 8,24)   h_hi|h_lo  -> (after gemm_qkv) Wf1_b|Wf2_b   (attn_cvt2 fills)
//   [24,40)   qh|ql      -> (after attn)   x1 (f32)
//   [40,72)   kh|kl|vt|attnout -> (after Wo) ff (bf16 4096x4096)
//   [72,80)   h2
// ---------------------------------------------------------------------------
extern "C" void kernel_launch(void* const* d_in, const int* in_sizes, int n_in,
                              void* d_out, int out_size, void* d_ws,
                              size_t ws_size, hipStream_t stream) {
  const float* x = (const float*)d_in[0];
  const float* g1 = (const float*)d_in[2];
  const float* b1 = (const float*)d_in[3];
  const float* g2 = (const float*)d_in[4];
  const float* b2 = (const float*)d_in[5];
  const float* Wq = (const float*)d_in[6];
  const float* Wk = (const float*)d_in[7];
  const float* Wv = (const float*)d_in[8];
  const float* Wo = (const float*)d_in[9];
  const float* Wf1 = (const float*)d_in[10];
  const float* Wf2 = (const float*)d_in[11];
  char* ws = (char*)d_ws;
  const size_t MB = 1024 * 1024;
  const size_t M1 = 1u << 20;
  bf16* Wq_b = (bf16*)ws;
  bf16* Wk_b = Wq_b + 1 * M1;
  bf16* Wv_b = Wq_b + 2 * M1;
  bf16* Wo_b = Wq_b + 3 * M1;
  bf16* h_hi = (bf16*)(ws + 8 * MB);
  bf16* h_lo = (bf16*)(ws + 16 * MB);
  bf16* Wf1_b = h_hi;  // alias: h dead after gemm_qkv; attn_cvt2 fills
  bf16* Wf2_b = h_lo;
  bf16* qh = (bf16*)(ws + 24 * MB);
  bf16* ql = (bf16*)(ws + 32 * MB);
  bf16* kh = (bf16*)(ws + 40 * MB);
  bf16* kl = (bf16*)(ws + 48 * MB);
  bf16* vt = (bf16*)(ws + 56 * MB);
  bf16* attnout = (bf16*)(ws + 64 * MB);
  float* x1 = (float*)qh;  // alias: qh/ql dead after attn
  bf16* h2 = (bf16*)(ws + 72 * MB);
  bf16* ff = kh;  // alias: kh/kl/vt/attnout dead after Wo GEMM
  float* outp = (float*)d_out;

  // 1) LN1 (split bf16 hi/lo) + cvt4 (attention weights) in one launch
  ln1_cvt4<<<8192, 256, 0, stream>>>(x, g1, b1, h_hi, h_lo, Wq, Wk, Wv, Wo,
                                     Wq_b);
  // 2) Q,K (merged split bf16, q pre-scaled 1/8) + V^T (single-pass) fused
  gemm_qkv<<<dim3(24, 32), 256, 0, stream>>>(h_hi, h_lo, Wq_b, Wk_b, Wv_b, qh,
                                             ql, kh, kl, vt);
  // 3) attention (blocks 0..1023) + cvt2 FF weights (blocks 1024..9215);
  //    cvt2 overwrites h_hi/h_lo (dead after step 2)
  attn_cvt2<<<9216, 256, 0, stream>>>(qh, ql, kh, kl, vt, attnout, Wf1, Wf2,
                                      Wf1_b);
  // 4) x1 = x + attnout @ Wo^T   (f32; overwrites dead qh/ql) — 64N tiles
  gemm_bt64<2><<<dim3(16, 32), 256, 0, stream>>>(attnout, Wo_b, (void*)x1, x,
                                                 4096, 1024, 1024);
  // 5) LN2 -> h2 (bf16)
  ln_kernel<<<4096, 256, 0, stream>>>(x1, g2, b2, h2);
  // 6) ff = gelu(h2 @ Wff1^T)  (bf16; overwrites dead kh/kl/vt/attnout)
  gemm_bt<3, false><<<dim3(32, 32), 256, 0, stream>>>(
      h2, nullptr, Wf1_b, (void*)ff, nullptr, 4096, 4096, 1024);
  // 7) out = x1 + ff @ Wff2^T  (f32) — 64N tiles
  gemm_bt64<2><<<dim3(16, 32), 256, 0, stream>>>(ff, Wf2_b, (void*)outp, x1,
                                                 4096, 1024, 4096);
}

// Round 11
// 418.727 us; speedup vs baseline: 1.1661x; 1.0897x over previous
//
#include <hip/hip_runtime.h>

typedef __bf16 bf16;
typedef bf16 bf16x8 __attribute__((ext_vector_type(8)));
typedef bf16 bf16x4 __attribute__((ext_vector_type(4)));
typedef float f32x4 __attribute__((ext_vector_type(4)));

// ---------------------------------------------------------------------------
// async global->LDS 16B copy (wave-uniform LDS base + lane*16 placement)
// ---------------------------------------------------------------------------
static __device__ __forceinline__ void async16(const void* g, void* l) {
  __builtin_amdgcn_global_load_lds((__attribute__((address_space(1))) void*)g,
                                   (__attribute__((address_space(3))) void*)l,
                                   16, 0, 0);
}

// DPP row_ror:N within 16-lane rows (VALU-only cross-lane; no LDS pipe).
template <int N>
static __device__ __forceinline__ float ror16(float x) {
  const int y =
      __builtin_amdgcn_update_dpp(0, __float_as_int(x), 0x120 | N, 0xf, 0xf, true);
  return __int_as_float(y);
}
static __device__ __forceinline__ float rowmax16(float x) {
  x = fmaxf(x, ror16<8>(x));
  x = fmaxf(x, ror16<4>(x));
  x = fmaxf(x, ror16<2>(x));
  x = fmaxf(x, ror16<1>(x));
  return x;
}
static __device__ __forceinline__ float rowsum16(float x) {
  x += ror16<8>(x);
  x += ror16<4>(x);
  x += ror16<2>(x);
  x += ror16<1>(x);
  return x;
}

// ---------------------------------------------------------------------------
// LN1 (split bf16 hi/lo) fused with cvt4 (attention weights f32->bf16).
// blocks [0,4096): LN rows; blocks [4096,8192): weight conversion chunks.
// ---------------------------------------------------------------------------
__global__ __launch_bounds__(256) void ln1_cvt4(
    const float* __restrict__ x, const float* __restrict__ g,
    const float* __restrict__ b, bf16* __restrict__ hi, bf16* __restrict__ lo,
    const float* __restrict__ Wq, const float* __restrict__ Wk,
    const float* __restrict__ Wv, const float* __restrict__ Wo,
    bf16* __restrict__ wdst) {
  const int tid = threadIdx.x;
  if (blockIdx.x >= 4096) {  // cvt4 path
    const size_t i = ((size_t)(blockIdx.x - 4096) * 256 + tid) * 4;
    const size_t M1 = 1u << 20;
    const float* src = (i < M1) ? Wq : (i < 2 * M1) ? Wk : (i < 3 * M1) ? Wv : Wo;
    const size_t off = i & (M1 - 1);
    const float4 v = *(const float4*)(src + off);
    bf16x4 o = {(bf16)v.x, (bf16)v.y, (bf16)v.z, (bf16)v.w};
    *(bf16x4*)(wdst + i) = o;
    return;
  }
  const int row = blockIdx.x;
  const float* xr = x + (size_t)row * 1024;
  float v[4];
  float s1 = 0.f, s2 = 0.f;
#pragma unroll
  for (int j = 0; j < 4; ++j) {
    v[j] = xr[j * 256 + tid];
    s1 += v[j];
    s2 += v[j] * v[j];
  }
#pragma unroll
  for (int off = 1; off < 64; off <<= 1) {
    s1 += __shfl_xor(s1, off);
    s2 += __shfl_xor(s2, off);
  }
  __shared__ float ws1[4], ws2[4];
  const int wid = tid >> 6;
  if ((tid & 63) == 0) {
    ws1[wid] = s1;
    ws2[wid] = s2;
  }
  __syncthreads();
  s1 = ws1[0] + ws1[1] + ws1[2] + ws1[3];
  s2 = ws2[0] + ws2[1] + ws2[2] + ws2[3];
  const float mu = s1 * (1.f / 1024.f);
  const float var = s2 * (1.f / 1024.f) - mu * mu;
  const float rstd = 1.0f / sqrtf(var + 1e-5f);
#pragma unroll
  for (int j = 0; j < 4; ++j) {
    const int cc = j * 256 + tid;
    const float y = (v[j] - mu) * rstd * g[cc] + b[cc];
    const bf16 yh = (bf16)y;
    hi[(size_t)row * 1024 + cc] = yh;
    lo[(size_t)row * 1024 + cc] = (bf16)(y - (float)yh);
  }
}

// ---------------------------------------------------------------------------
// LayerNorm over D=1024 (f32 input), one block per row (non-split).
// ---------------------------------------------------------------------------
__global__ __launch_bounds__(256) void ln_kernel(
    const float* __restrict__ x, const float* __restrict__ g,
    const float* __restrict__ b, bf16* __restrict__ hi) {
  const int row = blockIdx.x;
  const int tid = threadIdx.x;
  const float* xr = x + (size_t)row * 1024;
  float v[4];
  float s1 = 0.f, s2 = 0.f;
#pragma unroll
  for (int j = 0; j < 4; ++j) {
    v[j] = xr[j * 256 + tid];
    s1 += v[j];
    s2 += v[j] * v[j];
  }
#pragma unroll
  for (int off = 1; off < 64; off <<= 1) {
    s1 += __shfl_xor(s1, off);
    s2 += __shfl_xor(s2, off);
  }
  __shared__ float ws1[4], ws2[4];
  const int wid = tid >> 6;
  if ((tid & 63) == 0) {
    ws1[wid] = s1;
    ws2[wid] = s2;
  }
  __syncthreads();
  s1 = ws1[0] + ws1[1] + ws1[2] + ws1[3];
  s2 = ws2[0] + ws2[1] + ws2[2] + ws2[3];
  const float mu = s1 * (1.f / 1024.f);
  const float var = s2 * (1.f / 1024.f) - mu * mu;
  const float rstd = 1.0f / sqrtf(var + 1e-5f);
#pragma unroll
  for (int j = 0; j < 4; ++j) {
    const int cc = j * 256 + tid;
    const float y = (v[j] - mu) * rstd * g[cc] + b[cc];
    hi[(size_t)row * 1024 + cc] = (bf16)y;
  }
}

// ---------------------------------------------------------------------------
// GEMM: C[M,N] = A[M,K] * B[N,K]^T   (m97 structure, BK=64 as two BK=32
// sub-buffers per barrier pair: per-buffer layout identical to the verified
// stride-32 pattern, but HALF the barriers — amortizes the vmcnt(0) drain).
// EPI: 0 = f32 store, 2 = f32(acc + R[f32]), 3 = bf16 gelu(acc),
//      5 = bf16 store transposed to V^T global layout (b,h,d,t)
// smem: caller-provided (>= 16384 bf16).
// ---------------------------------------------------------------------------
template <int EPI>
static __device__ __forceinline__ void gemm_body(
    const bf16* __restrict__ A, const bf16* __restrict__ B,
    void* __restrict__ Cv, const float* __restrict__ R, bf16* smem, int col0,
    int row0, int M, int N, int K) {
  bf16* sA0 = smem;          // 128 x 32
  bf16* sA1 = smem + 4096;   // 128 x 32 (k+32)
  bf16* sB0 = smem + 8192;   // 128 x 32
  bf16* sB1 = smem + 12288;  // 128 x 32 (k+32)
  const int tid = threadIdx.x;
  const int lane = tid & 63;
  const int wid = tid >> 6;
  const int wm = wid >> 1, wn = wid & 1;

  f32x4 acc[4][4];
  const f32x4 fzero = {0.f, 0.f, 0.f, 0.f};
#pragma unroll
  for (int i = 0; i < 4; ++i)
#pragma unroll
    for (int j = 0; j < 4; ++j) acc[i][j] = fzero;

  const int nk = K >> 6;
  const int r0 = tid >> 2, c0 = (tid & 3) << 3;
  const int r1 = (256 + tid) >> 2, c1 = ((256 + tid) & 3) << 3;
  const int wofs0 = (wid << 6) * 8;  // wave-uniform LDS offsets
  const int wofs1 = (256 + (wid << 6)) * 8;

  for (int kt = 0; kt < nk; ++kt) {
    const int k0 = kt << 6;
    async16(A + (size_t)(row0 + r0) * K + k0 + c0, sA0 + wofs0);
    async16(A + (size_t)(row0 + r1) * K + k0 + c1, sA0 + wofs1);
    async16(A + (size_t)(row0 + r0) * K + k0 + 32 + c0, sA1 + wofs0);
    async16(A + (size_t)(row0 + r1) * K + k0 + 32 + c1, sA1 + wofs1);
    async16(B + (size_t)(col0 + r0) * K + k0 + c0, sB0 + wofs0);
    async16(B + (size_t)(col0 + r1) * K + k0 + c1, sB0 + wofs1);
    async16(B + (size_t)(col0 + r0) * K + k0 + 32 + c0, sB1 + wofs0);
    async16(B + (size_t)(col0 + r1) * K + k0 + 32 + c1, sB1 + wofs1);
    __syncthreads();
    const int fr = lane & 15, fq = (lane >> 4) << 3;
#pragma unroll
    for (int t = 0; t < 2; ++t) {
      const bf16* sA = t ? sA1 : sA0;
      const bf16* sB = t ? sB1 : sB0;
      bf16x8 af[4], bfr[4];
#pragma unroll
      for (int i = 0; i < 4; ++i)
        af[i] = *(const bf16x8*)&sA[(wm * 64 + i * 16 + fr) * 32 + fq];
#pragma unroll
      for (int j = 0; j < 4; ++j)
        bfr[j] = *(const bf16x8*)&sB[(wn * 64 + j * 16 + fr) * 32 + fq];
#pragma unroll
      for (int i = 0; i < 4; ++i)
#pragma unroll
        for (int j = 0; j < 4; ++j)
          acc[i][j] = __builtin_amdgcn_mfma_f32_16x16x32_bf16(
              af[i], bfr[j], acc[i][j], 0, 0, 0);
    }
    __syncthreads();
  }

  // C/D layout (m89-verified): col = lane&15, row = (lane>>4)*4 + reg
  const int fr = lane & 15, fq4 = (lane >> 4) << 2;
#pragma unroll
  for (int i = 0; i < 4; ++i) {
#pragma unroll
    for (int j = 0; j < 4; ++j) {
      const int rbase = row0 + wm * 64 + i * 16 + fq4;
      const int col = col0 + wn * 64 + j * 16 + fr;
      if constexpr (EPI == 5) {
        const int b = rbase >> 11, t = rbase & 2047;
        const int hh = col >> 6, d = col & 63;
        bf16x4 o4 = {(bf16)acc[i][j][0], (bf16)acc[i][j][1],
                     (bf16)acc[i][j][2], (bf16)acc[i][j][3]};
        *(bf16x4*)&((bf16*)Cv)[(((size_t)(b * 16 + hh)) * 64 + d) * 2048 + t] =
            o4;
      } else {
#pragma unroll
        for (int r = 0; r < 4; ++r) {
          const size_t idx = (size_t)(rbase + r) * N + col;
          const float val = acc[i][j][r];
          if constexpr (EPI == 0) {
            ((float*)Cv)[idx] = val;
          } else if constexpr (EPI == 2) {
            ((float*)Cv)[idx] = val + R[idx];
          } else {  // EPI == 3
            ((bf16*)Cv)[idx] =
                (bf16)(0.5f * val * (1.0f + erff(val * 0.7071067811865476f)));
          }
        }
      }
    }
  }
}

template <int EPI>
__global__ __launch_bounds__(256) void gemm_bt(
    const bf16* __restrict__ A, const bf16* __restrict__ B,
    void* __restrict__ Cv, const float* __restrict__ R, int M, int N, int K) {
  __shared__ bf16 smem[16384];
  gemm_body<EPI>(A, B, Cv, R, smem, blockIdx.x * 128, blockIdx.y * 128, M, N,
                 K);
}

// ---------------------------------------------------------------------------
// Merged split-K GEMM for q/k (BK=64, two sub-steps per barrier): stages
// A_hi, A_lo AND B each k-step (B loaded ONCE). Split bf16 hi/lo epilogue.
// ---------------------------------------------------------------------------
static __device__ __forceinline__ void gemm_split_merged(
    const bf16* __restrict__ A, const bf16* __restrict__ A2,
    const bf16* __restrict__ B, bf16* __restrict__ Chi, bf16* __restrict__ Clo,
    bf16* smem, float scale, int col0, int row0) {
  constexpr int K = 1024, N = 1024;
  bf16* sAh0 = smem;           // 128 x 32
  bf16* sAh1 = smem + 4096;    // k+32
  bf16* sAl0 = smem + 8192;
  bf16* sAl1 = smem + 12288;
  bf16* sB0 = smem + 16384;
  bf16* sB1 = smem + 20480;
  const int tid = threadIdx.x;
  const int lane = tid & 63;
  const int wid = tid >> 6;
  const int wm = wid >> 1, wn = wid & 1;

  f32x4 acc[4][4];
  const f32x4 fzero = {0.f, 0.f, 0.f, 0.f};
#pragma unroll
  for (int i = 0; i < 4; ++i)
#pragma unroll
    for (int j = 0; j < 4; ++j) acc[i][j] = fzero;

  const int r0 = tid >> 2, c0 = (tid & 3) << 3;
  const int r1 = (256 + tid) >> 2, c1 = ((256 + tid) & 3) << 3;
  const int wofs0 = (wid << 6) * 8;
  const int wofs1 = (256 + (wid << 6)) * 8;

  for (int kt = 0; kt < 16; ++kt) {
    const int k0 = kt << 6;
    async16(A + (size_t)(row0 + r0) * K + k0 + c0, sAh0 + wofs0);
    async16(A + (size_t)(row0 + r1) * K + k0 + c1, sAh0 + wofs1);
    async16(A + (size_t)(row0 + r0) * K + k0 + 32 + c0, sAh1 + wofs0);
    async16(A + (size_t)(row0 + r1) * K + k0 + 32 + c1, sAh1 + wofs1);
    async16(A2 + (size_t)(row0 + r0) * K + k0 + c0, sAl0 + wofs0);
    async16(A2 + (size_t)(row0 + r1) * K + k0 + c1, sAl0 + wofs1);
    async16(A2 + (size_t)(row0 + r0) * K + k0 + 32 + c0, sAl1 + wofs0);
    async16(A2 + (size_t)(row0 + r1) * K + k0 + 32 + c1, sAl1 + wofs1);
    async16(B + (size_t)(col0 + r0) * K + k0 + c0, sB0 + wofs0);
    async16(B + (size_t)(col0 + r1) * K + k0 + c1, sB0 + wofs1);
    async16(B + (size_t)(col0 + r0) * K + k0 + 32 + c0, sB1 + wofs0);
    async16(B + (size_t)(col0 + r1) * K + k0 + 32 + c1, sB1 + wofs1);
    __syncthreads();
    const int fr = lane & 15, fq = (lane >> 4) << 3;
#pragma unroll
    for (int t = 0; t < 2; ++t) {
      const bf16* sAh = t ? sAh1 : sAh0;
      const bf16* sAl = t ? sAl1 : sAl0;
      const bf16* sB = t ? sB1 : sB0;
      bf16x8 ah[4], al[4], bfr[4];
#pragma unroll
      for (int i = 0; i < 4; ++i) {
        ah[i] = *(const bf16x8*)&sAh[(wm * 64 + i * 16 + fr) * 32 + fq];
        al[i] = *(const bf16x8*)&sAl[(wm * 64 + i * 16 + fr) * 32 + fq];
      }
#pragma unroll
      for (int j = 0; j < 4; ++j)
        bfr[j] = *(const bf16x8*)&sB[(wn * 64 + j * 16 + fr) * 32 + fq];
#pragma unroll
      for (int i = 0; i < 4; ++i)
#pragma unroll
        for (int j = 0; j < 4; ++j) {
          acc[i][j] = __builtin_amdgcn_mfma_f32_16x16x32_bf16(
              ah[i], bfr[j], acc[i][j], 0, 0, 0);
          acc[i][j] = __builtin_amdgcn_mfma_f32_16x16x32_bf16(
              al[i], bfr[j], acc[i][j], 0, 0, 0);
        }
    }
    __syncthreads();
  }

  const int fr = lane & 15, fq4 = (lane >> 4) << 2;
#pragma unroll
  for (int i = 0; i < 4; ++i)
#pragma unroll
    for (int j = 0; j < 4; ++j) {
      const int rbase = row0 + wm * 64 + i * 16 + fq4;
      const int col = col0 + wn * 64 + j * 16 + fr;
#pragma unroll
      for (int r = 0; r < 4; ++r) {
        const size_t idx = (size_t)(rbase + r) * N + col;
        const float vs = acc[i][j][r] * scale;
        const bf16 hi = (bf16)vs;
        Chi[idx] = hi;
        Clo[idx] = (bf16)(vs - (float)hi);
      }
    }
}

// Q,K,V fused: grid (24, 32). bx>>3: 0=q (merged split, scale folds 1/8 AND
// log2e for the exp2 softmax), 1=k (merged split), 2=v (single-pass bf16 h,
// transposed store). ONE shared buffer (49152 B) for both paths.
__global__ __launch_bounds__(256) void gemm_qkv(
    const bf16* __restrict__ A, const bf16* __restrict__ A2,
    const bf16* __restrict__ Bq, const bf16* __restrict__ Bk,
    const bf16* __restrict__ Bv, bf16* qh, bf16* ql, bf16* kh, bf16* kl,
    bf16* vt) {
  __shared__ bf16 smem[24576];
  const int which = blockIdx.x >> 3;
  const int col0 = (blockIdx.x & 7) * 128, row0 = blockIdx.y * 128;
  if (which == 2) {
    gemm_body<5>(A, Bv, (void*)vt, nullptr, smem, col0, row0, 4096, 1024,
                 1024);
  } else {
    gemm_split_merged(A, A2, which ? Bk : Bq, which ? kh : qh, which ? kl : ql,
                      smem, which ? 1.0f : 0.125f * 1.44269504088896f, col0,
                      row0);
  }
}

// ---------------------------------------------------------------------------
// 128x64-tile GEMM (BK=64 two-sub-step) for N=1024 outputs (2 blocks/CU).
// ---------------------------------------------------------------------------
template <int EPI>
__global__ __launch_bounds__(256) void gemm_bt64(
    const bf16* __restrict__ A, const bf16* __restrict__ B,
    void* __restrict__ Cv, const float* __restrict__ R, int M, int N, int K) {
  __shared__ bf16 smem[12288];  // A0,A1: 4096 each; B0,B1: 2048 each
  bf16* sA0 = smem;
  bf16* sA1 = smem + 4096;
  bf16* sB0 = smem + 8192;
  bf16* sB1 = smem + 10240;
  const int col0 = blockIdx.x * 64, row0 = blockIdx.y * 128;
  const int tid = threadIdx.x;
  const int lane = tid & 63;
  const int wid = tid >> 6;
  const int wm = wid >> 1, wn = wid & 1;

  f32x4 acc[4][2];
  const f32x4 fzero = {0.f, 0.f, 0.f, 0.f};
#pragma unroll
  for (int i = 0; i < 4; ++i)
#pragma unroll
    for (int j = 0; j < 2; ++j) acc[i][j] = fzero;

  const int nk = K >> 6;
  const int r0 = tid >> 2, c0 = (tid & 3) << 3;
  const int r1 = (256 + tid) >> 2, c1 = ((256 + tid) & 3) << 3;
  const int wofs0 = (wid << 6) * 8;
  const int wofs1 = (256 + (wid << 6)) * 8;

  for (int kt = 0; kt < nk; ++kt) {
    const int k0 = kt << 6;
    async16(A + (size_t)(row0 + r0) * K + k0 + c0, sA0 + wofs0);
    async16(A + (size_t)(row0 + r1) * K + k0 + c1, sA0 + wofs1);
    async16(A + (size_t)(row0 + r0) * K + k0 + 32 + c0, sA1 + wofs0);
    async16(A + (size_t)(row0 + r1) * K + k0 + 32 + c1, sA1 + wofs1);
    async16(B + (size_t)(col0 + r0) * K + k0 + c0, sB0 + wofs0);
    async16(B + (size_t)(col0 + r0) * K + k0 + 32 + c0, sB1 + wofs0);
    __syncthreads();
    const int fr = lane & 15, fq = (lane >> 4) << 3;
#pragma unroll
    for (int t = 0; t < 2; ++t) {
      const bf16* sA = t ? sA1 : sA0;
      const bf16* sB = t ? sB1 : sB0;
      bf16x8 af[4], bfr[2];
#pragma unroll
      for (int i = 0; i < 4; ++i)
        af[i] = *(const bf16x8*)&sA[(wm * 64 + i * 16 + fr) * 32 + fq];
#pragma unroll
      for (int j = 0; j < 2; ++j)
        bfr[j] = *(const bf16x8*)&sB[(wn * 32 + j * 16 + fr) * 32 + fq];
#pragma unroll
      for (int i = 0; i < 4; ++i)
#pragma unroll
        for (int j = 0; j < 2; ++j)
          acc[i][j] = __builtin_amdgcn_mfma_f32_16x16x32_bf16(
              af[i], bfr[j], acc[i][j], 0, 0, 0);
    }
    __syncthreads();
  }

  const int fr = lane & 15, fq4 = (lane >> 4) << 2;
#pragma unroll
  for (int i = 0; i < 4; ++i) {
#pragma unroll
    for (int j = 0; j < 2; ++j) {
      const int rbase = row0 + wm * 64 + i * 16 + fq4;
      const int col = col0 + wn * 32 + j * 16 + fr;
#pragma unroll
      for (int r = 0; r < 4; ++r) {
        const size_t idx = (size_t)(rbase + r) * N + col;
        const float val = acc[i][j][r];
        if constexpr (EPI == 2) {
          ((float*)Cv)[idx] = val + R[idx];
        } else {
          ((float*)Cv)[idx] = val;
        }
      }
    }
  }
}

// ---------------------------------------------------------------------------
// MFMA causal flash attention (64-query blocks, 88 VGPR) fused with cvt2
// (FF weights f32->bf16) in blocks [1024, 9216) — copy blocks backfill CUs
// during attn's causal tail.
//  - logits are in log2 domain (log2e folded into q scale) -> exp2f softmax
//  - Q fragments from global; next K/V tile register-prefetched
//  - 2 barriers/iter; P tile wave-private (stride 76, intra-wave RAW only)
//  - DPP softmax; LDS 37376 B -> 4 blocks/CU
//  - plain __launch_bounds__(256): (256,4) caused scratch spill — keep off
//  - 128-query variant (r9) regressed: VGPR 148 -> occupancy 8.8% — keep 64q
// ---------------------------------------------------------------------------
__global__ __launch_bounds__(256) void attn_cvt2(
    const bf16* __restrict__ qh_g, const bf16* __restrict__ ql_g,
    const bf16* __restrict__ kh_g, const bf16* __restrict__ kl_g,
    const bf16* __restrict__ vt_g, bf16* __restrict__ out,
    const float* __restrict__ Wf1, const float* __restrict__ Wf2,
    bf16* __restrict__ wdst) {
  __shared__ bf16 lds[18688];  // 37376 B
  const int tid = threadIdx.x;
  if (blockIdx.x >= 1024) {  // cvt2 path
    const size_t i = ((size_t)(blockIdx.x - 1024) * 256 + tid) * 4;
    const size_t M4 = 4u << 20;
    const float* src = (i < M4) ? Wf1 : Wf2;
    const size_t off = (i < M4) ? i : i - M4;
    const float4 v = *(const float4*)(src + off);
    bf16x4 o4 = {(bf16)v.x, (bf16)v.y, (bf16)v.z, (bf16)v.w};
    *(bf16x4*)(wdst + i) = o4;
    return;
  }
  bf16* Kh = lds;          // 64 x 72
  bf16* Kl = lds + 4608;   // 64 x 72
  bf16* Vt = lds + 9216;   // 64 x 72, rows = dim d, cols = key
  bf16* Ps = lds + 13824;  // 4 waves x 16 x 76 (wave-private)

  const int bid = blockIdx.x;
  const int qt = 31 - (bid >> 5);  // long blocks first
  const int h = bid & 15;
  const int b = (bid >> 4) & 1;
  const int t0 = qt << 6;
  const int w = tid >> 6;
  const int lane = tid & 63;
  const int c = lane & 15;
  const int quad = lane >> 4;

  const int r0 = tid >> 3, c0 = (tid & 7) << 3;
  const int r1 = (tid + 256) >> 3, c1 = ((tid + 256) & 7) << 3;

  // Q fragments straight from global (once per block)
  const size_t qrow =
      ((size_t)(b * 2048 + t0 + w * 16 + c)) * 1024 + h * 64 + quad * 8;
  bf16x8 aqh[2], aql[2];
  aqh[0] = *(const bf16x8*)&qh_g[qrow];
  aqh[1] = *(const bf16x8*)&qh_g[qrow + 32];
  aql[0] = *(const bf16x8*)&ql_g[qrow];
  aql[1] = *(const bf16x8*)&ql_g[qrow + 32];

  f32x4 o[4];
  const f32x4 fzero = {0.f, 0.f, 0.f, 0.f};
#pragma unroll
  for (int j = 0; j < 4; ++j) o[j] = fzero;
  float m_i[4] = {-3e38f, -3e38f, -3e38f, -3e38f};
  float l_i[4] = {0.f, 0.f, 0.f, 0.f};

  const size_t vtb = ((size_t)(b * 16 + h)) * 64 * 2048;  // + d*2048 + t
  const size_t kband = ((size_t)(b * 2048)) * 1024 + h * 64;

  bf16x8 gk[6];  // register prefetch of next K/V tile
  {
    gk[0] = *(const bf16x8*)&kh_g[kband + (size_t)r0 * 1024 + c0];
    gk[1] = *(const bf16x8*)&kh_g[kband + (size_t)r1 * 1024 + c1];
    gk[2] = *(const bf16x8*)&kl_g[kband + (size_t)r0 * 1024 + c0];
    gk[3] = *(const bf16x8*)&kl_g[kband + (size_t)r1 * 1024 + c1];
    gk[4] = *(const bf16x8*)&vt_g[vtb + (size_t)r0 * 2048 + c0];
    gk[5] = *(const bf16x8*)&vt_g[vtb + (size_t)r1 * 2048 + c1];
  }

  for (int kt = 0; kt <= qt; ++kt) {
    __syncthreads();  // (A) prev tile's fragment reads done before restage
    *(bf16x8*)&Kh[r0 * 72 + c0] = gk[0];
    *(bf16x8*)&Kh[r1 * 72 + c1] = gk[1];
    *(bf16x8*)&Kl[r0 * 72 + c0] = gk[2];
    *(bf16x8*)&Kl[r1 * 72 + c1] = gk[3];
    *(bf16x8*)&Vt[r0 * 72 + c0] = gk[4];
    *(bf16x8*)&Vt[r1 * 72 + c1] = gk[5];
    __syncthreads();  // (B) staging visible

    if (kt < qt) {  // prefetch next tile; latency hidden behind compute
      const int kb1 = (kt + 1) << 6;
      const size_t kbase = kband + (size_t)kb1 * 1024;
      gk[0] = *(const bf16x8*)&kh_g[kbase + (size_t)r0 * 1024 + c0];
      gk[1] = *(const bf16x8*)&kh_g[kbase + (size_t)r1 * 1024 + c1];
      gk[2] = *(const bf16x8*)&kl_g[kbase + (size_t)r0 * 1024 + c0];
      gk[3] = *(const bf16x8*)&kl_g[kbase + (size_t)r1 * 1024 + c1];
      gk[4] = *(const bf16x8*)&vt_g[vtb + (size_t)r0 * 2048 + kb1 + c0];
      gk[5] = *(const bf16x8*)&vt_g[vtb + (size_t)r1 * 2048 + kb1 + c1];
    }

    bf16x8 bkh[4][2], bkl[4][2];
#pragma unroll
    for (int j = 0; j < 4; ++j)
#pragma unroll
      for (int s = 0; s < 2; ++s) {
        bkh[j][s] = *(const bf16x8*)&Kh[(j * 16 + c) * 72 + s * 32 + quad * 8];
        bkl[j][s] = *(const bf16x8*)&Kl[(j * 16 + c) * 72 + s * 32 + quad * 8];
      }

    f32x4 s4[4];
#pragma unroll
    for (int j = 0; j < 4; ++j) s4[j] = fzero;
#pragma unroll
    for (int j = 0; j < 4; ++j)
#pragma unroll
      for (int s = 0; s < 2; ++s) {
        s4[j] = __builtin_amdgcn_mfma_f32_16x16x32_bf16(aqh[s], bkh[j][s], s4[j], 0, 0, 0);
        s4[j] = __builtin_amdgcn_mfma_f32_16x16x32_bf16(aqh[s], bkl[j][s], s4[j], 0, 0, 0);
        s4[j] = __builtin_amdgcn_mfma_f32_16x16x32_bf16(aql[s], bkh[j][s], s4[j], 0, 0, 0);
      }

    if (kt == qt) {  // diagonal tile: strict-upper mask (t0 == kb)
#pragma unroll
      for (int j = 0; j < 4; ++j)
#pragma unroll
        for (int r = 0; r < 4; ++r)
          if (j * 16 + c > w * 16 + quad * 4 + r) s4[j][r] = -3e38f;
    }

    float al[4], p[4][4];
#pragma unroll
    for (int r = 0; r < 4; ++r) {
      float mt = fmaxf(fmaxf(s4[0][r], s4[1][r]), fmaxf(s4[2][r], s4[3][r]));
      mt = rowmax16(mt);  // DPP row reduce
      const float mn = fmaxf(m_i[r], mt);
      al[r] = exp2f(m_i[r] - mn);  // logits already in log2 domain
      float ps = 0.f;
#pragma unroll
      for (int j = 0; j < 4; ++j) {
        p[r][j] = exp2f(s4[j][r] - mn);
        ps += p[r][j];
      }
      ps = rowsum16(ps);  // DPP row reduce
      l_i[r] = l_i[r] * al[r] + ps;
      m_i[r] = mn;
#pragma unroll
      for (int j = 0; j < 4; ++j) o[j][r] *= al[r];
    }

    // P -> wave-private region, stride 76 (conflict-free; intra-wave RAW only)
    bf16* Pw = Ps + w * 16 * 76;
#pragma unroll
    for (int r = 0; r < 4; ++r)
#pragma unroll
      for (int j = 0; j < 4; ++j)
        Pw[(quad * 4 + r) * 76 + j * 16 + c] = (bf16)p[r][j];

    bf16x8 ap[2], bv[4][2];
#pragma unroll
    for (int s = 0; s < 2; ++s)
      ap[s] = *(const bf16x8*)&Pw[c * 76 + s * 32 + quad * 8];
#pragma unroll
    for (int j = 0; j < 4; ++j)
#pragma unroll
      for (int s = 0; s < 2; ++s)
        bv[j][s] = *(const bf16x8*)&Vt[(j * 16 + c) * 72 + s * 32 + quad * 8];
#pragma unroll
    for (int j = 0; j < 4; ++j)
#pragma unroll
      for (int s = 0; s < 2; ++s)
        o[j] = __builtin_amdgcn_mfma_f32_16x16x32_bf16(ap[s], bv[j][s], o[j], 0, 0, 0);
  }

#pragma unroll
  for (int r = 0; r < 4; ++r) {
    const float inv = 1.0f / l_i[r];
#pragma unroll
    for (int j = 0; j < 4; ++j) {
      const size_t oi =
          ((size_t)(b * 2048 + t0 + w * 16 + quad * 4 + r)) * 1024 + h * 64 +
          j * 16 + c;
      out[oi] = (bf16)(o[j][r] * inv);
    }
  }
}

// ---------------------------------------------------------------------------
// Workspace plan (80 MiB peak; >104 MiB previously corrupted harness memory):
//   [ 0, 8)   Wq|Wk|Wv|Wo bf16
//   [ 8,24)   h_hi|h_lo  -> (after gemm_qkv) Wf1_b|Wf2_b   (attn_cvt2 fills)
//   [24,40)   qh|ql      -> (after attn)   x1 (f32)
//   [40,72)   kh|kl|vt|attnout -> (after Wo) ff (bf16 4096x4096)
//   [72,80)   h2
// ---------------------------------------------------------------------------
extern "C" void kernel_launch(void* const* d_in, const int* in_sizes, int n_in,
                              void* d_out, int out_size, void* d_ws,
                              size_t ws_size, hipStream_t stream) {
  const float* x = (const float*)d_in[0];
  const float* g1 = (const float*)d_in[2];
  const float* b1 = (const float*)d_in[3];
  const float* g2 = (const float*)d_in[4];
  const float* b2 = (const float*)d_in[5];
  const float* Wq = (const float*)d_in[6];
  const float* Wk = (const float*)d_in[7];
  const float* Wv = (const float*)d_in[8];
  const float* Wo = (const float*)d_in[9];
  const float* Wf1 = (const float*)d_in[10];
  const float* Wf2 = (const float*)d_in[11];
  char* ws = (char*)d_ws;
  const size_t MB = 1024 * 1024;
  const size_t M1 = 1u << 20;
  bf16* Wq_b = (bf16*)ws;
  bf16* Wk_b = Wq_b + 1 * M1;
  bf16* Wv_b = Wq_b + 2 * M1;
  bf16* Wo_b = Wq_b + 3 * M1;
  bf16* h_hi = (bf16*)(ws + 8 * MB);
  bf16* h_lo = (bf16*)(ws + 16 * MB);
  bf16* Wf1_b = h_hi;  // alias: h dead after gemm_qkv; attn_cvt2 fills
  bf16* Wf2_b = h_lo;
  bf16* qh = (bf16*)(ws + 24 * MB);
  bf16* ql = (bf16*)(ws + 32 * MB);
  bf16* kh = (bf16*)(ws + 40 * MB);
  bf16* kl = (bf16*)(ws + 48 * MB);
  bf16* vt = (bf16*)(ws + 56 * MB);
  bf16* attnout = (bf16*)(ws + 64 * MB);
  float* x1 = (float*)qh;  // alias: qh/ql dead after attn
  bf16* h2 = (bf16*)(ws + 72 * MB);
  bf16* ff = kh;  // alias: kh/kl/vt/attnout dead after Wo GEMM
  float* outp = (float*)d_out;

  // 1) LN1 (split bf16 hi/lo) + cvt4 (attention weights) in one launch
  ln1_cvt4<<<8192, 256, 0, stream>>>(x, g1, b1, h_hi, h_lo, Wq, Wk, Wv, Wo,
                                     Wq_b);
  // 2) Q,K (merged split bf16, q scale = 1/8*log2e) + V^T fused
  gemm_qkv<<<dim3(24, 32), 256, 0, stream>>>(h_hi, h_lo, Wq_b, Wk_b, Wv_b, qh,
                                             ql, kh, kl, vt);
  // 3) attention (blocks 0..1023) + cvt2 FF weights (blocks 1024..9215)
  attn_cvt2<<<9216, 256, 0, stream>>>(qh, ql, kh, kl, vt, attnout, Wf1, Wf2,
                                      Wf1_b);
  // 4) x1 = x + attnout @ Wo^T   (f32; overwrites dead qh/ql) — 64N tiles
  gemm_bt64<2><<<dim3(16, 32), 256, 0, stream>>>(attnout, Wo_b, (void*)x1, x,
                                                 4096, 1024, 1024);
  // 5) LN2 -> h2 (bf16)
  ln_kernel<<<4096, 256, 0, stream>>>(x1, g2, b2, h2);
  // 6) ff = gelu(h2 @ Wff1^T)  (bf16; overwrites dead kh/kl/vt/attnout)
  gemm_bt<3><<<dim3(32, 32), 256, 0, stream>>>(h2, Wf1_b, (void*)ff, nullptr,
                                               4096, 4096, 1024);
  // 7) out = x1 + ff @ Wff2^T  (f32) — 64N tiles
  gemm_bt64<2><<<dim3(16, 32), 256, 0, stream>>>(ff, Wf2_b, (void*)outp, x1,
                                                 4096, 1024, 4096);
}